// Round 6
// baseline (484.912 us; speedup 1.0000x reference)
//
#include <hip/hip_runtime.h>
#include <hip/hip_bf16.h>

#define GNN_N 50000
#define GNN_E 600000

typedef unsigned int uint;
typedef unsigned short ushort;
using short8 = __attribute__((ext_vector_type(8))) short;
using f32x4  = __attribute__((ext_vector_type(4))) float;

__device__ __forceinline__ float leaky02(float x) { return x > 0.f ? x : 0.2f * x; }
__device__ __forceinline__ ushort f2b(float f) {  // RNE float->bf16
    uint u = __float_as_uint(f);
    return (ushort)((u + 0x7fffu + ((u >> 16) & 1u)) >> 16);
}
__device__ __forceinline__ float b2f(ushort b) { return __uint_as_float(((uint)b) << 16); }

// ---------------- degree / CSR build ----------------
__global__ void gnn_deg_init(float* deg, int n) {
    int i = blockIdx.x * blockDim.x + threadIdx.x;
    if (i < n) deg[i] = 1.0f;  // self-loop weight
}
__global__ void gnn_hist(const int* __restrict__ dst, const float* __restrict__ ew,
                         int* __restrict__ cnt, float* __restrict__ deg, int e) {
    int i = blockIdx.x * blockDim.x + threadIdx.x;
    if (i >= e) return;
    int d = dst[i];
    atomicAdd(&cnt[d], 1);
    atomicAdd(&deg[d], ew[i]);
}
__global__ void gnn_deg_fin(float* deg, int n) {
    int i = blockIdx.x * blockDim.x + threadIdx.x;
    if (i < n) deg[i] = rsqrtf(deg[i]);
}
__global__ void gnn_scan1(const int* __restrict__ cnt, int* __restrict__ row_ptr,
                          int* __restrict__ blksum, int n) {
    __shared__ int sh[256];
    int tid = threadIdx.x;
    int base = blockIdx.x * 1024 + tid * 4;
    int v0 = (base + 0 < n) ? cnt[base + 0] : 0;
    int v1 = (base + 1 < n) ? cnt[base + 1] : 0;
    int v2 = (base + 2 < n) ? cnt[base + 2] : 0;
    int v3 = (base + 3 < n) ? cnt[base + 3] : 0;
    int tsum = v0 + v1 + v2 + v3;
    sh[tid] = tsum;
    __syncthreads();
    for (int off = 1; off < 256; off <<= 1) {
        int t = (tid >= off) ? sh[tid - off] : 0;
        __syncthreads();
        sh[tid] += t;
        __syncthreads();
    }
    int excl = sh[tid] - tsum;
    if (base + 0 < n) row_ptr[base + 0] = excl; excl += v0;
    if (base + 1 < n) row_ptr[base + 1] = excl; excl += v1;
    if (base + 2 < n) row_ptr[base + 2] = excl; excl += v2;
    if (base + 3 < n) row_ptr[base + 3] = excl;
    if (tid == 255) blksum[blockIdx.x] = sh[255];
}
__global__ void gnn_scan2(int* blksum, int nblk, int* row_ptr_end, int total) {
    if (threadIdx.x == 0 && blockIdx.x == 0) {
        int run = 0;
        for (int b = 0; b < nblk; ++b) { int t = blksum[b]; blksum[b] = run; run += t; }
        *row_ptr_end = total;
    }
}
__global__ void gnn_scan3(int* row_ptr, const int* __restrict__ blksum, int n) {
    int i = blockIdx.x * blockDim.x + threadIdx.x;
    if (i < n) row_ptr[i] += blksum[i >> 10];
}
__global__ void gnn_scatter(const int* __restrict__ src, const int* __restrict__ dst,
                            const float* __restrict__ ew, const float* __restrict__ dinv,
                            const int* __restrict__ row_ptr, int* __restrict__ fill,
                            int* __restrict__ esrc, float* __restrict__ ecw, int e) {
    int i = blockIdx.x * blockDim.x + threadIdx.x;
    if (i >= e) return;
    int d = dst[i];
    int s = src[i];
    int pos = row_ptr[d] + atomicAdd(&fill[d], 1);
    esrc[pos] = s;
    ecw[pos] = dinv[s] * ew[i] * dinv[d];
}

// ---------------- casts ----------------
__global__ void gnn_cast_bf16(const float* __restrict__ in, ushort* __restrict__ out, int n4) {
    int i = blockIdx.x * 256 + threadIdx.x;
    if (i >= n4) return;
    float4 v = ((const float4*)in)[i];
    ushort4 o;
    o.x = f2b(v.x); o.y = f2b(v.y); o.z = f2b(v.z); o.w = f2b(v.w);
    ((ushort4*)out)[i] = o;
}
// B[K][N] fp32 -> Bt[N][K] bf16
__global__ void gnn_transpose_cast(const float* __restrict__ B, ushort* __restrict__ Bt,
                                   int K, int N) {
    int idx = blockIdx.x * 256 + threadIdx.x;
    if (idx >= K * N) return;
    int k = idx / N, n = idx - k * N;
    Bt[(size_t)n * K + k] = f2b(B[idx]);
}

// fold att into weight space: wa_t[j][k] = sum_c W[k][h*64+c]*att[h][c], j<8 src, j>=8 dst
__global__ void gnn_fold_att(const float* __restrict__ W, const float* __restrict__ att_src,
                             const float* __restrict__ att_dst, float* __restrict__ wa_t) {
    int t = blockIdx.x * 256 + threadIdx.x;
    if (t >= 16 * 128) return;
    int j = t >> 7;
    int k = t & 127;
    int h = j & 7;
    const float* av = (j < 8) ? att_src : att_dst;
    float s = 0.f;
    for (int c = 0; c < 64; ++c) s += W[(size_t)k * 512 + h * 64 + c] * av[h * 64 + c];
    wa_t[j * 128 + k] = s;
}

// ---------------- bf16 MFMA GEMM: C[M][N] = A[M][K] @ Bt[N][K]^T, all bf16 ----------------
__global__ __launch_bounds__(256) void gnn_mfma_gemm(const ushort* __restrict__ A,
                                                     const ushort* __restrict__ Bt,
                                                     ushort* __restrict__ C,
                                                     int M, int N, int K) {
    __shared__ ushort As[64 * 40];
    __shared__ ushort Bs[64 * 40];
    const int tid = threadIdx.x;
    const int wv = tid >> 6, lane = tid & 63;
    const int g = lane >> 4, r = lane & 15;
    const int brow = blockIdx.y << 6, bcol = blockIdx.x << 6;

    const int srow = tid >> 2;
    const int skoff = (tid & 3) << 3;
    int arow = brow + srow;
    if (arow >= M) arow = M - 1;
    const ushort* Ap = A + (size_t)arow * K + skoff;
    const ushort* Bp = Bt + (size_t)(bcol + srow) * K + skoff;
    ushort* AsW = &As[srow * 40 + skoff];
    ushort* BsW = &Bs[srow * 40 + skoff];

    f32x4 acc[4] = {};

    for (int k0 = 0; k0 < K; k0 += 32) {
        *(short8*)AsW = *(const short8*)(Ap + k0);
        *(short8*)BsW = *(const short8*)(Bp + k0);
        __syncthreads();
        short8 bfrag = *(const short8*)&Bs[(wv * 16 + r) * 40 + g * 8];
#pragma unroll
        for (int mb = 0; mb < 4; ++mb) {
            short8 afrag = *(const short8*)&As[(mb * 16 + r) * 40 + g * 8];
            acc[mb] = __builtin_amdgcn_mfma_f32_16x16x32_bf16(afrag, bfrag, acc[mb], 0, 0, 0);
        }
        __syncthreads();
    }

    const int col = bcol + wv * 16 + r;
#pragma unroll
    for (int mb = 0; mb < 4; ++mb) {
        int rowb = brow + mb * 16 + g * 4;
#pragma unroll
        for (int rr = 0; rr < 4; ++rr) {
            int row = rowb + rr;
            if (row < M) C[(size_t)row * N + col] = f2b(acc[mb][rr]);
        }
    }
}

// ---------------- fp32 tiled GEMM -> bf16 out (GEMM3 only) ----------------
__global__ __launch_bounds__(256) void gnn_sgemm64_b16(const float* __restrict__ A,
                                                       const float* __restrict__ B,
                                                       ushort* __restrict__ C,
                                                       int M, int N, int K) {
    __shared__ float As[16][68];
    __shared__ float Bs[16][68];
    const int tid = threadIdx.x;
    const int tx = tid & 15;
    const int ty = tid >> 4;
    const int brow = blockIdx.y << 6;
    const int bcol = blockIdx.x << 6;

    const int am = tid >> 2;
    const int ak = (tid & 3) << 2;
    const int bk = tid >> 4;
    const int bn = (tid & 15) << 2;

    const int arow = brow + am;
    const bool avalid = arow < M;
    const float* Aptr = A + (size_t)(avalid ? arow : 0) * K + ak;
    const float* Bptr = B + (size_t)bk * N + bcol + bn;

    float acc[4][4] = {};

    for (int k0 = 0; k0 < K; k0 += 16) {
        float4 av = avalid ? *(const float4*)(Aptr + k0) : make_float4(0.f, 0.f, 0.f, 0.f);
        float4 bv = *(const float4*)(Bptr + (size_t)k0 * N);
        As[ak + 0][am] = av.x;
        As[ak + 1][am] = av.y;
        As[ak + 2][am] = av.z;
        As[ak + 3][am] = av.w;
        *(float4*)&Bs[bk][bn] = bv;
        __syncthreads();
#pragma unroll
        for (int k = 0; k < 16; ++k) {
            float4 a = *(const float4*)&As[k][ty << 2];
            float4 b = *(const float4*)&Bs[k][tx << 2];
            acc[0][0] += a.x * b.x; acc[0][1] += a.x * b.y; acc[0][2] += a.x * b.z; acc[0][3] += a.x * b.w;
            acc[1][0] += a.y * b.x; acc[1][1] += a.y * b.y; acc[1][2] += a.y * b.z; acc[1][3] += a.y * b.w;
            acc[2][0] += a.z * b.x; acc[2][1] += a.z * b.y; acc[2][2] += a.z * b.z; acc[2][3] += a.z * b.w;
            acc[3][0] += a.w * b.x; acc[3][1] += a.w * b.y; acc[3][2] += a.w * b.z; acc[3][3] += a.w * b.w;
        }
        __syncthreads();
    }
#pragma unroll
    for (int i = 0; i < 4; ++i) {
        int row = brow + (ty << 2) + i;
        if (row < M) {
            ushort4 v;
            v.x = f2b(acc[i][0]); v.y = f2b(acc[i][1]); v.z = f2b(acc[i][2]); v.w = f2b(acc[i][3]);
            *(ushort4*)(C + (size_t)row * N + bcol + (tx << 2)) = v;
        }
    }
}

// ---------------- GCN1 per-node gather: bf16 in, bf16 out ----------------
__global__ __launch_bounds__(256) void gnn_gcn_node128(const int* __restrict__ row_ptr,
                                                       const int* __restrict__ esrc,
                                                       const float* __restrict__ ecw,
                                                       const float* __restrict__ dinv,
                                                       const ushort* __restrict__ hb,
                                                       const float* __restrict__ b,
                                                       ushort* __restrict__ out, int n) {
    int v = blockIdx.x * 4 + (threadIdx.x >> 6);
    int lane = threadIdx.x & 63;
    if (v >= n) return;
    float di = dinv[v];
    float sc = di * di;
    uint us = *(const uint*)(hb + (size_t)v * 128 + 2 * lane);
    float acc0 = sc * __uint_as_float(us << 16);
    float acc1 = sc * __uint_as_float(us & 0xffff0000u);
    int beg = row_ptr[v], end = row_ptr[v + 1];
    for (int p = beg; p < end; ++p) {
        int s = esrc[p];
        float cw = ecw[p];
        uint u = *(const uint*)(hb + (size_t)s * 128 + 2 * lane);
        acc0 += cw * __uint_as_float(u << 16);
        acc1 += cw * __uint_as_float(u & 0xffff0000u);
    }
    float o0 = acc0 + b[2 * lane];
    float o1 = acc1 + b[2 * lane + 1];
    o0 = o0 > 0.f ? o0 : 0.f;
    o1 = o1 > 0.f ? o1 : 0.f;
    uint o = (uint)f2b(o0) | ((uint)f2b(o1) << 16);
    *(uint*)(out + (size_t)v * 128 + 2 * lane) = o;
}

// ------- a_s/a_d via folded weights: [N,128]bf16 @ wa_t[16][128] -------
__global__ __launch_bounds__(256) void gnn_gat_asd(const ushort* __restrict__ g1b,
                                                   const float* __restrict__ wa_t,
                                                   float* __restrict__ a_s,
                                                   float* __restrict__ a_d, int n) {
    __shared__ float swa[16 * 128];
    for (int i = threadIdx.x; i < 16 * 128; i += 256) swa[i] = wa_t[i];
    __syncthreads();
    int v = blockIdx.x * 4 + (threadIdx.x >> 6);
    int lane = threadIdx.x & 63;
    if (v >= n) return;
    uint u = *(const uint*)(g1b + (size_t)v * 128 + 2 * lane);
    float v0 = __uint_as_float(u << 16);
    float v1 = __uint_as_float(u & 0xffff0000u);
    float part[16];
#pragma unroll
    for (int j = 0; j < 16; ++j)
        part[j] = v0 * swa[j * 128 + 2 * lane] + v1 * swa[j * 128 + 2 * lane + 1];
#pragma unroll
    for (int m = 1; m < 64; m <<= 1) {
#pragma unroll
        for (int j = 0; j < 16; ++j) part[j] += __shfl_xor(part[j], m);
    }
    if (lane == 0) {
#pragma unroll
        for (int j = 0; j < 8; ++j) {
            a_s[(size_t)v * 8 + j] = part[j];
            a_d[(size_t)v * 8 + j] = part[8 + j];
        }
    }
}

// ------- GAT pass A: unnormalized p per (edge, head) + per-(node,head) sums -------
__global__ __launch_bounds__(256) void gnn_gat_alpha(const int* __restrict__ row_ptr,
                                                     const int* __restrict__ esrc,
                                                     const float* __restrict__ a_s,
                                                     const float* __restrict__ a_d,
                                                     float* __restrict__ palpha,
                                                     float* __restrict__ ssum, int n) {
    int v = blockIdx.x * 4 + (threadIdx.x >> 6);
    int lane = threadIdx.x & 63;
    if (v >= n) return;
    int h = lane & 7, slot = lane >> 3;
    float adh = a_d[(size_t)v * 8 + h];
    float sloc = (slot == 0) ? __expf(leaky02(a_s[(size_t)v * 8 + h] + adh)) : 0.f;  // self
    int beg = row_ptr[v], end = row_ptr[v + 1];
    for (int p = beg + slot; p < end; p += 8) {
        int s = esrc[p];
        float pp = __expf(leaky02(a_s[(size_t)s * 8 + h] + adh));
        palpha[(size_t)p * 8 + h] = pp;
        sloc += pp;
    }
    sloc += __shfl_xor(sloc, 8);
    sloc += __shfl_xor(sloc, 16);
    sloc += __shfl_xor(sloc, 32);
    if (slot == 0) ssum[(size_t)v * 8 + h] = sloc + 1e-16f;
}

// ------- GAT pass B: weighted gather; lane L owns head L>>3, channels (L&7)*8..+7 -------
__global__ __launch_bounds__(256) void gnn_gat_gather(const int* __restrict__ row_ptr,
                                                      const int* __restrict__ esrc,
                                                      const float* __restrict__ a_s,
                                                      const float* __restrict__ a_d,
                                                      const float* __restrict__ palpha,
                                                      const float* __restrict__ ssum,
                                                      const ushort* __restrict__ h2,
                                                      const float* __restrict__ gat_b,
                                                      float* __restrict__ out, int n) {
    int v = blockIdx.x * 4 + (threadIdx.x >> 6);
    int lane = threadIdx.x & 63;
    if (v >= n) return;
    const int hd = lane >> 3;

    float vh[8];
    {   // self edge: p_self recomputed (1 exp/lane)
        float ps = __expf(leaky02(a_s[(size_t)v * 8 + hd] + a_d[(size_t)v * 8 + hd]));
        short8 hs = *(const short8*)(h2 + (size_t)v * 512 + lane * 8);
#pragma unroll
        for (int j = 0; j < 8; ++j) vh[j] = ps * b2f((ushort)hs[j]);
    }
    int beg = row_ptr[v], end = row_ptr[v + 1];
    for (int p = beg; p < end; ++p) {
        int s = esrc[p];
        float pp = palpha[(size_t)p * 8 + hd];
        short8 hs = *(const short8*)(h2 + (size_t)s * 512 + lane * 8);
#pragma unroll
        for (int j = 0; j < 8; ++j) vh[j] += pp * b2f((ushort)hs[j]);
    }
    float rs = 1.f / ssum[(size_t)v * 8 + hd];
#pragma unroll
    for (int j = 0; j < 8; ++j) vh[j] *= rs;
    // mean over heads: reduce across lane bits 3,4,5
#pragma unroll
    for (int m = 8; m < 64; m <<= 1) {
#pragma unroll
        for (int j = 0; j < 8; ++j) vh[j] += __shfl_xor(vh[j], m);
    }
    if (lane < 8) {
        float* op = out + (size_t)v * 64 + lane * 8;
#pragma unroll
        for (int j = 0; j < 8; ++j) {
            float o = 0.125f * vh[j] + gat_b[lane * 8 + j];
            op[j] = o > 0.f ? o : 0.f;
        }
    }
}

// ---------------- GCN2 per-node gather + fused FC -> d_out ----------------
__global__ __launch_bounds__(256) void gnn_gcn_node64_fc(const int* __restrict__ row_ptr,
                                                         const int* __restrict__ esrc,
                                                         const float* __restrict__ ecw,
                                                         const float* __restrict__ dinv,
                                                         const ushort* __restrict__ hb,
                                                         const float* __restrict__ b,
                                                         const float* __restrict__ fc_w,
                                                         const float* __restrict__ fc_b,
                                                         float* __restrict__ out, int n) {
    int v = blockIdx.x * 4 + (threadIdx.x >> 6);
    int lane = threadIdx.x & 63;
    if (v >= n) return;
    float di = dinv[v];
    float acc = di * di * b2f(hb[(size_t)v * 64 + lane]);
    int beg = row_ptr[v], end = row_ptr[v + 1];
    for (int p = beg; p < end; ++p) {
        int s = esrc[p];
        acc += ecw[p] * b2f(hb[(size_t)s * 64 + lane]);
    }
    float o = acc + b[lane];
    o = o > 0.f ? o : 0.f;
    float val = o * fc_w[lane];
#pragma unroll
    for (int m = 32; m; m >>= 1) val += __shfl_xor(val, m);
    if (lane == 0) out[v] = val + fc_b[0];
}

// ---------------- launch ----------------
extern "C" void kernel_launch(void* const* d_in, const int* in_sizes, int n_in,
                              void* d_out, int out_size, void* d_ws, size_t ws_size,
                              hipStream_t stream) {
    const float* x       = (const float*)d_in[0];
    const int*   ei      = (const int*)d_in[1];
    const float* ew      = (const float*)d_in[2];
    const float* gc1_w   = (const float*)d_in[3];
    const float* gc1_b   = (const float*)d_in[4];
    const float* gat_w   = (const float*)d_in[5];
    const float* att_src = (const float*)d_in[6];
    const float* att_dst = (const float*)d_in[7];
    const float* gat_b   = (const float*)d_in[8];
    const float* gc2_w   = (const float*)d_in[9];
    const float* gc2_b   = (const float*)d_in[10];
    const float* fc_w    = (const float*)d_in[11];
    const float* fc_b    = (const float*)d_in[12];
    float* out = (float*)d_out;

    const int N = GNN_N;
    const int E = in_sizes[2];
    const int* src = ei;
    const int* dst = ei + E;

    // ---- workspace layout (~152 MB) ----
    char* p = (char*)d_ws;
    ushort* h2b = (ushort*)p; p += (size_t)N * 512 * 2;   // 51.2 MB [N][512] bf16
    ushort* xb  = (ushort*)p; p += (size_t)N * 256 * 2;   // 25.6 MB
    ushort* h1b = (ushort*)p; p += (size_t)N * 128 * 2;   // 12.8 MB
    ushort* g1b = (ushort*)p; p += (size_t)N * 128 * 2;   // 12.8 MB
    float*  g2  = (float*)p;  p += (size_t)N * 64 * 4;    // 12.8 MB
    ushort* h3b = (ushort*)p; p += (size_t)N * 64 * 2;    // 6.4 MB
    float* palpha = (float*)p; p += (size_t)GNN_E * 8 * 4; // 19.2 MB
    float*  ssum = (float*)p; p += (size_t)N * 8 * 4;     // 1.6 MB
    ushort* w1t = (ushort*)p; p += (size_t)128 * 256 * 2; // 64 KB
    ushort* w2t = (ushort*)p; p += (size_t)512 * 128 * 2; // 128 KB
    float*  wa_t = (float*)p; p += 16 * 128 * 4;          // 8 KB
    float*  a_s = (float*)p;  p += (size_t)N * 8 * 4;
    float*  a_d = (float*)p;  p += (size_t)N * 8 * 4;
    float*  dinv = (float*)p; p += (size_t)N * 4;
    int* row_ptr = (int*)p;   p += (size_t)(N + 64) * 4;
    int* esrc = (int*)p;      p += (size_t)E * 4;
    float* ecw = (float*)p;   p += (size_t)E * 4;
    int* cnt = (int*)p;       p += (size_t)N * 4;
    int* fill = (int*)p;      p += (size_t)N * 4;
    int* blksum = (int*)p;    p += 4096;

    auto cdiv = [](long a, long b) { return (int)((a + b - 1) / b); };

    // ---- CSR build + symmetric norm ----
    hipMemsetAsync(cnt, 0, (size_t)N * 4, stream);
    hipMemsetAsync(fill, 0, (size_t)N * 4, stream);
    gnn_deg_init<<<cdiv(N, 256), 256, 0, stream>>>(dinv, N);
    gnn_hist<<<cdiv(E, 256), 256, 0, stream>>>(dst, ew, cnt, dinv, E);
    gnn_deg_fin<<<cdiv(N, 256), 256, 0, stream>>>(dinv, N);
    const int nblk = cdiv(N, 1024);
    gnn_scan1<<<nblk, 256, 0, stream>>>(cnt, row_ptr, blksum, N);
    gnn_scan2<<<1, 64, 0, stream>>>(blksum, nblk, row_ptr + N, E);
    gnn_scan3<<<cdiv(N, 256), 256, 0, stream>>>(row_ptr, blksum, N);
    gnn_scatter<<<cdiv(E, 256), 256, 0, stream>>>(src, dst, ew, dinv, row_ptr, fill, esrc, ecw, E);

    // ---- casts / folds ----
    gnn_cast_bf16<<<cdiv((long)N * 256 / 4, 256), 256, 0, stream>>>(x, xb, N * 256 / 4);
    gnn_transpose_cast<<<cdiv(256 * 128, 256), 256, 0, stream>>>(gc1_w, w1t, 256, 128);
    gnn_transpose_cast<<<cdiv(128 * 512, 256), 256, 0, stream>>>(gat_w, w2t, 128, 512);
    gnn_fold_att<<<8, 256, 0, stream>>>(gat_w, att_src, att_dst, wa_t);

    // ---- GCN1 ----
    {
        dim3 grid(128 / 64, cdiv(N, 64));
        gnn_mfma_gemm<<<grid, 256, 0, stream>>>(xb, w1t, h1b, N, 128, 256);
    }
    gnn_gcn_node128<<<cdiv(N, 4), 256, 0, stream>>>(row_ptr, esrc, ecw, dinv, h1b, gc1_b, g1b, N);

    // ---- GAT ----
    {
        dim3 grid(512 / 64, cdiv(N, 64));
        gnn_mfma_gemm<<<grid, 256, 0, stream>>>(g1b, w2t, h2b, N, 512, 128);
    }
    gnn_gat_asd<<<cdiv(N, 4), 256, 0, stream>>>(g1b, wa_t, a_s, a_d, N);
    gnn_gat_alpha<<<cdiv(N, 4), 256, 0, stream>>>(row_ptr, esrc, a_s, a_d, palpha, ssum, N);
    gnn_gat_gather<<<cdiv(N, 4), 256, 0, stream>>>(row_ptr, esrc, a_s, a_d, palpha, ssum,
                                                   h2b, gat_b, g2, N);

    // ---- GCN2 + FC ----
    {
        dim3 grid(64 / 64, cdiv(N, 64));
        gnn_sgemm64_b16<<<grid, 256, 0, stream>>>(g2, gc2_w, h3b, N, 64, 64);
    }
    gnn_gcn_node64_fc<<<cdiv(N, 4), 256, 0, stream>>>(row_ptr, esrc, ecw, dinv, h3b, gc2_b,
                                                      fc_w, fc_b, out, N);
}

// Round 7
// 385.658 us; speedup vs baseline: 1.2574x; 1.2574x over previous
//
#include <hip/hip_runtime.h>
#include <hip/hip_bf16.h>

#define GNN_N 50000
#define GNN_E 600000

typedef unsigned int uint;
typedef unsigned short ushort;
using short8 = __attribute__((ext_vector_type(8))) short;
using f32x4  = __attribute__((ext_vector_type(4))) float;

__device__ __forceinline__ float leaky02(float x) { return x > 0.f ? x : 0.2f * x; }
__device__ __forceinline__ ushort f2b(float f) {  // RNE float->bf16
    uint u = __float_as_uint(f);
    return (ushort)((u + 0x7fffu + ((u >> 16) & 1u)) >> 16);
}
__device__ __forceinline__ float b2f(ushort b) { return __uint_as_float(((uint)b) << 16); }

// ---------------- degree / CSR build ----------------
__global__ void gnn_deg_init(float* deg, int n) {
    int i = blockIdx.x * blockDim.x + threadIdx.x;
    if (i < n) deg[i] = 1.0f;  // self-loop weight
}
__global__ void gnn_hist(const int* __restrict__ dst, const float* __restrict__ ew,
                         int* __restrict__ cnt, float* __restrict__ deg, int e) {
    int i = blockIdx.x * blockDim.x + threadIdx.x;
    if (i >= e) return;
    int d = dst[i];
    atomicAdd(&cnt[d], 1);
    atomicAdd(&deg[d], ew[i]);
}
__global__ void gnn_deg_fin(float* deg, int n) {
    int i = blockIdx.x * blockDim.x + threadIdx.x;
    if (i < n) deg[i] = rsqrtf(deg[i]);
}
__global__ void gnn_scan1(const int* __restrict__ cnt, int* __restrict__ row_ptr,
                          int* __restrict__ blksum, int n) {
    __shared__ int sh[256];
    int tid = threadIdx.x;
    int base = blockIdx.x * 1024 + tid * 4;
    int v0 = (base + 0 < n) ? cnt[base + 0] : 0;
    int v1 = (base + 1 < n) ? cnt[base + 1] : 0;
    int v2 = (base + 2 < n) ? cnt[base + 2] : 0;
    int v3 = (base + 3 < n) ? cnt[base + 3] : 0;
    int tsum = v0 + v1 + v2 + v3;
    sh[tid] = tsum;
    __syncthreads();
    for (int off = 1; off < 256; off <<= 1) {
        int t = (tid >= off) ? sh[tid - off] : 0;
        __syncthreads();
        sh[tid] += t;
        __syncthreads();
    }
    int excl = sh[tid] - tsum;
    if (base + 0 < n) row_ptr[base + 0] = excl; excl += v0;
    if (base + 1 < n) row_ptr[base + 1] = excl; excl += v1;
    if (base + 2 < n) row_ptr[base + 2] = excl; excl += v2;
    if (base + 3 < n) row_ptr[base + 3] = excl;
    if (tid == 255) blksum[blockIdx.x] = sh[255];
}
__global__ void gnn_scan2(int* blksum, int nblk, int* row_ptr_end, int total) {
    if (threadIdx.x == 0 && blockIdx.x == 0) {
        int run = 0;
        for (int b = 0; b < nblk; ++b) { int t = blksum[b]; blksum[b] = run; run += t; }
        *row_ptr_end = total;
    }
}
__global__ void gnn_scan3(int* row_ptr, const int* __restrict__ blksum, int n) {
    int i = blockIdx.x * blockDim.x + threadIdx.x;
    if (i < n) row_ptr[i] += blksum[i >> 10];
}
__global__ void gnn_scatter(const int* __restrict__ src, const int* __restrict__ dst,
                            const float* __restrict__ ew, const float* __restrict__ dinv,
                            const int* __restrict__ row_ptr, int* __restrict__ fill,
                            int* __restrict__ esrc, float* __restrict__ ecw, int e) {
    int i = blockIdx.x * blockDim.x + threadIdx.x;
    if (i >= e) return;
    int d = dst[i];
    int s = src[i];
    int pos = row_ptr[d] + atomicAdd(&fill[d], 1);
    esrc[pos] = s;
    ecw[pos] = dinv[s] * ew[i] * dinv[d];
}

// ---------------- casts / folds ----------------
__global__ void gnn_cast_bf16(const float* __restrict__ in, ushort* __restrict__ out, int n4) {
    int i = blockIdx.x * 256 + threadIdx.x;
    if (i >= n4) return;
    float4 v = ((const float4*)in)[i];
    ushort4 o;
    o.x = f2b(v.x); o.y = f2b(v.y); o.z = f2b(v.z); o.w = f2b(v.w);
    ((ushort4*)out)[i] = o;
}
// B[K][N] fp32 -> Bt[N][K] bf16
__global__ void gnn_transpose_cast(const float* __restrict__ B, ushort* __restrict__ Bt,
                                   int K, int N) {
    int idx = blockIdx.x * 256 + threadIdx.x;
    if (idx >= K * N) return;
    int k = idx / N, n = idx - k * N;
    Bt[(size_t)n * K + k] = f2b(B[idx]);
}
// fold att into weight space: wa_t[j][k] = sum_c W[k][h*64+c]*att[h][c], j<8 src, j>=8 dst
__global__ void gnn_fold_att(const float* __restrict__ W, const float* __restrict__ att_src,
                             const float* __restrict__ att_dst, float* __restrict__ wa_t) {
    int t = blockIdx.x * 256 + threadIdx.x;
    if (t >= 16 * 128) return;
    int j = t >> 7;
    int k = t & 127;
    int h = j & 7;
    const float* av = (j < 8) ? att_src : att_dst;
    float s = 0.f;
    for (int c = 0; c < 64; ++c) s += W[(size_t)k * 512 + h * 64 + c] * av[h * 64 + c];
    wa_t[j * 128 + k] = s;
}

// ---------------- bf16 MFMA GEMM: C[M][N] = A[M][K] @ Bt[N][K]^T ----------------
__global__ __launch_bounds__(256) void gnn_mfma_gemm(const ushort* __restrict__ A,
                                                     const ushort* __restrict__ Bt,
                                                     ushort* __restrict__ C,
                                                     int M, int N, int K) {
    __shared__ ushort As[64 * 40];
    __shared__ ushort Bs[64 * 40];
    const int tid = threadIdx.x;
    const int wv = tid >> 6, lane = tid & 63;
    const int g = lane >> 4, r = lane & 15;
    const int brow = blockIdx.y << 6, bcol = blockIdx.x << 6;

    const int srow = tid >> 2;
    const int skoff = (tid & 3) << 3;
    int arow = brow + srow;
    if (arow >= M) arow = M - 1;
    const ushort* Ap = A + (size_t)arow * K + skoff;
    const ushort* Bp = Bt + (size_t)(bcol + srow) * K + skoff;
    ushort* AsW = &As[srow * 40 + skoff];
    ushort* BsW = &Bs[srow * 40 + skoff];

    f32x4 acc[4] = {};

    for (int k0 = 0; k0 < K; k0 += 32) {
        *(short8*)AsW = *(const short8*)(Ap + k0);
        *(short8*)BsW = *(const short8*)(Bp + k0);
        __syncthreads();
        short8 bfrag = *(const short8*)&Bs[(wv * 16 + r) * 40 + g * 8];
#pragma unroll
        for (int mb = 0; mb < 4; ++mb) {
            short8 afrag = *(const short8*)&As[(mb * 16 + r) * 40 + g * 8];
            acc[mb] = __builtin_amdgcn_mfma_f32_16x16x32_bf16(afrag, bfrag, acc[mb], 0, 0, 0);
        }
        __syncthreads();
    }

    const int col = bcol + wv * 16 + r;
#pragma unroll
    for (int mb = 0; mb < 4; ++mb) {
        int rowb = brow + mb * 16 + g * 4;
#pragma unroll
        for (int rr = 0; rr < 4; ++rr) {
            int row = rowb + rr;
            if (row < M) C[(size_t)row * N + col] = f2b(acc[mb][rr]);
        }
    }
}

// ------- GCN1 gather + fused bias/relu + fused attention dots (asd) -------
__global__ __launch_bounds__(256) void gnn_gcn_node128_asd(const int* __restrict__ row_ptr,
                                                           const int* __restrict__ esrc,
                                                           const float* __restrict__ ecw,
                                                           const float* __restrict__ dinv,
                                                           const ushort* __restrict__ hb,
                                                           const float* __restrict__ b,
                                                           const float* __restrict__ wa,
                                                           ushort* __restrict__ out,
                                                           float* __restrict__ a_s,
                                                           float* __restrict__ a_d, int n) {
    __shared__ float swa[16 * 128];
    for (int i = threadIdx.x; i < 16 * 128; i += 256) swa[i] = wa[i];
    __syncthreads();
    int v = blockIdx.x * 4 + (threadIdx.x >> 6);
    int lane = threadIdx.x & 63;
    if (v >= n) return;
    float di = dinv[v];
    float sc = di * di;
    uint us = *(const uint*)(hb + (size_t)v * 128 + 2 * lane);
    float acc0 = sc * __uint_as_float(us << 16);
    float acc1 = sc * __uint_as_float(us & 0xffff0000u);
    int beg = row_ptr[v], end = row_ptr[v + 1];
    int p = beg;
    for (; p + 4 <= end; p += 4) {
        int s0 = esrc[p], s1 = esrc[p + 1], s2 = esrc[p + 2], s3 = esrc[p + 3];
        float c0 = ecw[p], c1 = ecw[p + 1], c2 = ecw[p + 2], c3 = ecw[p + 3];
        uint u0 = *(const uint*)(hb + (size_t)s0 * 128 + 2 * lane);
        uint u1 = *(const uint*)(hb + (size_t)s1 * 128 + 2 * lane);
        uint u2 = *(const uint*)(hb + (size_t)s2 * 128 + 2 * lane);
        uint u3 = *(const uint*)(hb + (size_t)s3 * 128 + 2 * lane);
        acc0 += c0 * __uint_as_float(u0 << 16) + c1 * __uint_as_float(u1 << 16) +
                c2 * __uint_as_float(u2 << 16) + c3 * __uint_as_float(u3 << 16);
        acc1 += c0 * __uint_as_float(u0 & 0xffff0000u) + c1 * __uint_as_float(u1 & 0xffff0000u) +
                c2 * __uint_as_float(u2 & 0xffff0000u) + c3 * __uint_as_float(u3 & 0xffff0000u);
    }
    for (; p < end; ++p) {
        int s = esrc[p];
        float cw = ecw[p];
        uint u = *(const uint*)(hb + (size_t)s * 128 + 2 * lane);
        acc0 += cw * __uint_as_float(u << 16);
        acc1 += cw * __uint_as_float(u & 0xffff0000u);
    }
    float o0 = acc0 + b[2 * lane];
    float o1 = acc1 + b[2 * lane + 1];
    o0 = o0 > 0.f ? o0 : 0.f;
    o1 = o1 > 0.f ? o1 : 0.f;
    uint o = (uint)f2b(o0) | ((uint)f2b(o1) << 16);
    *(uint*)(out + (size_t)v * 128 + 2 * lane) = o;

    // fused a_s/a_d: dot(g1 row, wa[j]) for j=0..15
    float part[16];
#pragma unroll
    for (int j = 0; j < 16; ++j)
        part[j] = o0 * swa[j * 128 + 2 * lane] + o1 * swa[j * 128 + 2 * lane + 1];
#pragma unroll
    for (int m = 1; m < 64; m <<= 1) {
#pragma unroll
        for (int j = 0; j < 16; ++j) part[j] += __shfl_xor(part[j], m);
    }
    if (lane == 0) {
#pragma unroll
        for (int j = 0; j < 8; ++j) {
            a_s[(size_t)v * 8 + j] = part[j];
            a_d[(size_t)v * 8 + j] = part[8 + j];
        }
    }
}

// ------- GAT per-node: fused softmax+gather; lane = (head L>>3, chan-block L&7) -------
__global__ __launch_bounds__(256) void gnn_gat_node2(const int* __restrict__ row_ptr,
                                                     const int* __restrict__ esrc,
                                                     const float* __restrict__ a_s,
                                                     const float* __restrict__ a_d,
                                                     const ushort* __restrict__ h2,
                                                     const float* __restrict__ gat_b,
                                                     ushort* __restrict__ out, int n) {
    int v = blockIdx.x * 4 + (threadIdx.x >> 6);
    int lane = threadIdx.x & 63;
    if (v >= n) return;
    const int hd = lane >> 3;
    const float adh = a_d[(size_t)v * 8 + hd];

    float vh[8];
    float sl;
    {   // self edge
        float ps = __expf(leaky02(a_s[(size_t)v * 8 + hd] + adh));
        short8 q = *(const short8*)(h2 + (size_t)v * 512 + lane * 8);
        sl = ps;
#pragma unroll
        for (int j = 0; j < 8; ++j) vh[j] = ps * b2f((ushort)q[j]);
    }
    int beg = row_ptr[v], end = row_ptr[v + 1];
    int p = beg;
    for (; p + 4 <= end; p += 4) {
        int s0 = esrc[p], s1 = esrc[p + 1], s2 = esrc[p + 2], s3 = esrc[p + 3];
        float e0 = a_s[(size_t)s0 * 8 + hd];
        float e1 = a_s[(size_t)s1 * 8 + hd];
        float e2 = a_s[(size_t)s2 * 8 + hd];
        float e3 = a_s[(size_t)s3 * 8 + hd];
        short8 q0 = *(const short8*)(h2 + (size_t)s0 * 512 + lane * 8);
        short8 q1 = *(const short8*)(h2 + (size_t)s1 * 512 + lane * 8);
        short8 q2 = *(const short8*)(h2 + (size_t)s2 * 512 + lane * 8);
        short8 q3 = *(const short8*)(h2 + (size_t)s3 * 512 + lane * 8);
        float p0 = __expf(leaky02(e0 + adh));
        float p1 = __expf(leaky02(e1 + adh));
        float p2 = __expf(leaky02(e2 + adh));
        float p3 = __expf(leaky02(e3 + adh));
        sl += (p0 + p1) + (p2 + p3);
#pragma unroll
        for (int j = 0; j < 8; ++j)
            vh[j] += p0 * b2f((ushort)q0[j]) + p1 * b2f((ushort)q1[j]) +
                     p2 * b2f((ushort)q2[j]) + p3 * b2f((ushort)q3[j]);
    }
    for (; p < end; ++p) {
        int s = esrc[p];
        float pp = __expf(leaky02(a_s[(size_t)s * 8 + hd] + adh));
        short8 q = *(const short8*)(h2 + (size_t)s * 512 + lane * 8);
        sl += pp;
#pragma unroll
        for (int j = 0; j < 8; ++j) vh[j] += pp * b2f((ushort)q[j]);
    }
    float rs = 1.f / (sl + 1e-16f);
#pragma unroll
    for (int j = 0; j < 8; ++j) vh[j] *= rs;
    // mean over heads: reduce across lane bits 3,4,5
#pragma unroll
    for (int m = 8; m < 64; m <<= 1) {
#pragma unroll
        for (int j = 0; j < 8; ++j) vh[j] += __shfl_xor(vh[j], m);
    }
    if (lane < 8) {
        short8 o;
#pragma unroll
        for (int j = 0; j < 8; ++j) {
            float t = 0.125f * vh[j] + gat_b[lane * 8 + j];
            t = t > 0.f ? t : 0.f;
            o[j] = (short)f2b(t);
        }
        *(short8*)(out + (size_t)v * 64 + lane * 8) = o;
    }
}

// ---------------- GCN2 per-node gather + fused FC -> d_out ----------------
__global__ __launch_bounds__(256) void gnn_gcn_node64_fc(const int* __restrict__ row_ptr,
                                                         const int* __restrict__ esrc,
                                                         const float* __restrict__ ecw,
                                                         const float* __restrict__ dinv,
                                                         const ushort* __restrict__ hb,
                                                         const float* __restrict__ b,
                                                         const float* __restrict__ fc_w,
                                                         const float* __restrict__ fc_b,
                                                         float* __restrict__ out, int n) {
    int v = blockIdx.x * 4 + (threadIdx.x >> 6);
    int lane = threadIdx.x & 63;
    if (v >= n) return;
    float di = dinv[v];
    float acc = di * di * b2f(hb[(size_t)v * 64 + lane]);
    int beg = row_ptr[v], end = row_ptr[v + 1];
    int p = beg;
    for (; p + 4 <= end; p += 4) {
        int s0 = esrc[p], s1 = esrc[p + 1], s2 = esrc[p + 2], s3 = esrc[p + 3];
        float c0 = ecw[p], c1 = ecw[p + 1], c2 = ecw[p + 2], c3 = ecw[p + 3];
        float h0 = b2f(hb[(size_t)s0 * 64 + lane]);
        float h1 = b2f(hb[(size_t)s1 * 64 + lane]);
        float h2v = b2f(hb[(size_t)s2 * 64 + lane]);
        float h3v = b2f(hb[(size_t)s3 * 64 + lane]);
        acc += c0 * h0 + c1 * h1 + c2 * h2v + c3 * h3v;
    }
    for (; p < end; ++p) {
        int s = esrc[p];
        acc += ecw[p] * b2f(hb[(size_t)s * 64 + lane]);
    }
    float o = acc + b[lane];
    o = o > 0.f ? o : 0.f;
    float val = o * fc_w[lane];
#pragma unroll
    for (int m = 32; m; m >>= 1) val += __shfl_xor(val, m);
    if (lane == 0) out[v] = val + fc_b[0];
}

// ---------------- launch ----------------
extern "C" void kernel_launch(void* const* d_in, const int* in_sizes, int n_in,
                              void* d_out, int out_size, void* d_ws, size_t ws_size,
                              hipStream_t stream) {
    const float* x       = (const float*)d_in[0];
    const int*   ei      = (const int*)d_in[1];
    const float* ew      = (const float*)d_in[2];
    const float* gc1_w   = (const float*)d_in[3];
    const float* gc1_b   = (const float*)d_in[4];
    const float* gat_w   = (const float*)d_in[5];
    const float* att_src = (const float*)d_in[6];
    const float* att_dst = (const float*)d_in[7];
    const float* gat_b   = (const float*)d_in[8];
    const float* gc2_w   = (const float*)d_in[9];
    const float* gc2_b   = (const float*)d_in[10];
    const float* fc_w    = (const float*)d_in[11];
    const float* fc_b    = (const float*)d_in[12];
    float* out = (float*)d_out;

    const int N = GNN_N;
    const int E = in_sizes[2];
    const int* src = ei;
    const int* dst = ei + E;

    // ---- workspace layout (~125 MB) ----
    char* p = (char*)d_ws;
    ushort* h2b = (ushort*)p; p += (size_t)N * 512 * 2;   // 51.2 MB
    ushort* xb  = (ushort*)p; p += (size_t)N * 256 * 2;   // 25.6 MB
    ushort* h1b = (ushort*)p; p += (size_t)N * 128 * 2;   // 12.8 MB
    ushort* g1b = (ushort*)p; p += (size_t)N * 128 * 2;   // 12.8 MB
    ushort* g2b = (ushort*)p; p += (size_t)N * 64 * 2;    // 6.4 MB
    ushort* h3b = (ushort*)p; p += (size_t)N * 64 * 2;    // 6.4 MB
    ushort* w1t = (ushort*)p; p += (size_t)128 * 256 * 2; // 64 KB
    ushort* w2t = (ushort*)p; p += (size_t)512 * 128 * 2; // 128 KB
    ushort* w3t = (ushort*)p; p += (size_t)64 * 64 * 2;   // 8 KB
    float*  wa_t = (float*)p; p += 16 * 128 * 4;          // 8 KB
    float*  a_s = (float*)p;  p += (size_t)N * 8 * 4;
    float*  a_d = (float*)p;  p += (size_t)N * 8 * 4;
    float*  dinv = (float*)p; p += (size_t)N * 4;
    int* row_ptr = (int*)p;   p += (size_t)(N + 64) * 4;
    int* esrc = (int*)p;      p += (size_t)E * 4;
    float* ecw = (float*)p;   p += (size_t)E * 4;
    int* cnt = (int*)p;       p += (size_t)N * 4;
    int* fill = (int*)p;      p += (size_t)N * 4;   // adjacent to cnt: one memset
    int* blksum = (int*)p;    p += 4096;

    auto cdiv = [](long a, long b) { return (int)((a + b - 1) / b); };

    // ---- CSR build + symmetric norm ----
    hipMemsetAsync(cnt, 0, (size_t)N * 8, stream);  // cnt + fill
    gnn_deg_init<<<cdiv(N, 256), 256, 0, stream>>>(dinv, N);
    gnn_hist<<<cdiv(E, 256), 256, 0, stream>>>(dst, ew, cnt, dinv, E);
    gnn_deg_fin<<<cdiv(N, 256), 256, 0, stream>>>(dinv, N);
    const int nblk = cdiv(N, 1024);
    gnn_scan1<<<nblk, 256, 0, stream>>>(cnt, row_ptr, blksum, N);
    gnn_scan2<<<1, 64, 0, stream>>>(blksum, nblk, row_ptr + N, E);
    gnn_scan3<<<cdiv(N, 256), 256, 0, stream>>>(row_ptr, blksum, N);
    gnn_scatter<<<cdiv(E, 256), 256, 0, stream>>>(src, dst, ew, dinv, row_ptr, fill, esrc, ecw, E);

    // ---- casts / folds ----
    gnn_cast_bf16<<<cdiv((long)N * 256 / 4, 256), 256, 0, stream>>>(x, xb, N * 256 / 4);
    gnn_transpose_cast<<<cdiv(256 * 128, 256), 256, 0, stream>>>(gc1_w, w1t, 256, 128);
    gnn_transpose_cast<<<cdiv(128 * 512, 256), 256, 0, stream>>>(gat_w, w2t, 128, 512);
    gnn_transpose_cast<<<cdiv(64 * 64, 256), 256, 0, stream>>>(gc2_w, w3t, 64, 64);
    gnn_fold_att<<<8, 256, 0, stream>>>(gat_w, att_src, att_dst, wa_t);

    // ---- GCN1 (+ fused asd) ----
    {
        dim3 grid(128 / 64, cdiv(N, 64));
        gnn_mfma_gemm<<<grid, 256, 0, stream>>>(xb, w1t, h1b, N, 128, 256);
    }
    gnn_gcn_node128_asd<<<cdiv(N, 4), 256, 0, stream>>>(row_ptr, esrc, ecw, dinv, h1b, gc1_b,
                                                        wa_t, g1b, a_s, a_d, N);

    // ---- GAT ----
    {
        dim3 grid(512 / 64, cdiv(N, 64));
        gnn_mfma_gemm<<<grid, 256, 0, stream>>>(g1b, w2t, h2b, N, 512, 128);
    }
    gnn_gat_node2<<<cdiv(N, 4), 256, 0, stream>>>(row_ptr, esrc, a_s, a_d, h2b, gat_b, g2b, N);

    // ---- GCN2 + FC ----
    {
        dim3 grid(1, cdiv(N, 64));
        gnn_mfma_gemm<<<grid, 256, 0, stream>>>(g2b, w3t, h3b, N, 64, 64);
    }
    gnn_gcn_node64_fc<<<cdiv(N, 4), 256, 0, stream>>>(row_ptr, esrc, ecw, dinv, h3b, gc2_b,
                                                      fc_w, fc_b, out, N);
}

// Round 8
// 374.907 us; speedup vs baseline: 1.2934x; 1.0287x over previous
//
#include <hip/hip_runtime.h>
#include <hip/hip_bf16.h>

#define GNN_N 50000
#define GNN_E 600000

typedef unsigned int uint;
typedef unsigned short ushort;
using short8 = __attribute__((ext_vector_type(8))) short;
using f32x4  = __attribute__((ext_vector_type(4))) float;

__device__ __forceinline__ float leaky02(float x) { return x > 0.f ? x : 0.2f * x; }
__device__ __forceinline__ ushort f2b(float f) {  // RNE float->bf16
    uint u = __float_as_uint(f);
    return (ushort)((u + 0x7fffu + ((u >> 16) & 1u)) >> 16);
}
__device__ __forceinline__ float b2f(ushort b) { return __uint_as_float(((uint)b) << 16); }

// ---------------- degree / CSR build ----------------
// dinv starts memset-0; accumulate weighted degree, then rsqrt(1+acc) [self-loop weight 1]
__global__ void gnn_hist(const int* __restrict__ dst, const float* __restrict__ ew,
                         int* __restrict__ cnt, float* __restrict__ deg, int e) {
    int i = blockIdx.x * blockDim.x + threadIdx.x;
    if (i >= e) return;
    int d = dst[i];
    atomicAdd(&cnt[d], 1);
    atomicAdd(&deg[d], ew[i]);
}
__global__ void gnn_deg_fin(float* deg, int n) {
    int i = blockIdx.x * blockDim.x + threadIdx.x;
    if (i < n) deg[i] = rsqrtf(1.0f + deg[i]);
}
__global__ void gnn_scan1(const int* __restrict__ cnt, int* __restrict__ row_ptr,
                          int* __restrict__ blksum, int n) {
    __shared__ int sh[256];
    int tid = threadIdx.x;
    int base = blockIdx.x * 1024 + tid * 4;
    int v0 = (base + 0 < n) ? cnt[base + 0] : 0;
    int v1 = (base + 1 < n) ? cnt[base + 1] : 0;
    int v2 = (base + 2 < n) ? cnt[base + 2] : 0;
    int v3 = (base + 3 < n) ? cnt[base + 3] : 0;
    int tsum = v0 + v1 + v2 + v3;
    sh[tid] = tsum;
    __syncthreads();
    for (int off = 1; off < 256; off <<= 1) {
        int t = (tid >= off) ? sh[tid - off] : 0;
        __syncthreads();
        sh[tid] += t;
        __syncthreads();
    }
    int excl = sh[tid] - tsum;
    if (base + 0 < n) row_ptr[base + 0] = excl; excl += v0;
    if (base + 1 < n) row_ptr[base + 1] = excl; excl += v1;
    if (base + 2 < n) row_ptr[base + 2] = excl; excl += v2;
    if (base + 3 < n) row_ptr[base + 3] = excl;
    if (tid == 255) blksum[blockIdx.x] = sh[255];
}
__global__ void gnn_scan2(int* blksum, int nblk, int* row_ptr_end, int total) {
    if (threadIdx.x == 0 && blockIdx.x == 0) {
        int run = 0;
        for (int b = 0; b < nblk; ++b) { int t = blksum[b]; blksum[b] = run; run += t; }
        *row_ptr_end = total;
    }
}
__global__ void gnn_scan3(int* row_ptr, const int* __restrict__ blksum, int n) {
    int i = blockIdx.x * blockDim.x + threadIdx.x;
    if (i < n) row_ptr[i] += blksum[i >> 10];
}
__global__ void gnn_scatter(const int* __restrict__ src, const int* __restrict__ dst,
                            const float* __restrict__ ew, const float* __restrict__ dinv,
                            const int* __restrict__ row_ptr, int* __restrict__ fill,
                            int* __restrict__ esrc, float* __restrict__ ecw, int e) {
    int i = blockIdx.x * blockDim.x + threadIdx.x;
    if (i >= e) return;
    int d = dst[i];
    int s = src[i];
    int pos = row_ptr[d] + atomicAdd(&fill[d], 1);
    esrc[pos] = s;
    ecw[pos] = dinv[s] * ew[i] * dinv[d];
}

// ---------------- fused prep: 3 weight transpose-casts + att fold, one kernel ----------------
__global__ void gnn_prep(const float* __restrict__ gc1_w, const float* __restrict__ gat_w,
                         const float* __restrict__ gc2_w, const float* __restrict__ att_src,
                         const float* __restrict__ att_dst, ushort* __restrict__ w1t,
                         ushort* __restrict__ w2t, ushort* __restrict__ w3t,
                         float* __restrict__ wa_t) {
    int t = blockIdx.x * 256 + threadIdx.x;
    if (t < 32768) {                       // gc1_w [256][128] -> w1t[128][256]
        int k = t >> 7, n = t & 127;
        w1t[n * 256 + k] = f2b(gc1_w[t]);
        return;
    }
    t -= 32768;
    if (t < 65536) {                       // gat_w [128][512] -> w2t[512][128]
        int k = t >> 9, n = t & 511;
        w2t[n * 128 + k] = f2b(gat_w[t]);
        return;
    }
    t -= 65536;
    if (t < 4096) {                        // gc2_w [64][64] -> w3t[64][64]
        int k = t >> 6, n = t & 63;
        w3t[n * 64 + k] = f2b(gc2_w[t]);
        return;
    }
    t -= 4096;
    if (t < 2048) {                        // wa_t[16][128]: fold att into weight space
        int j = t >> 7, k = t & 127;
        int h = j & 7;
        const float* av = (j < 8) ? att_src : att_dst;
        float s = 0.f;
        for (int c = 0; c < 64; ++c) s += gat_w[(size_t)k * 512 + h * 64 + c] * av[h * 64 + c];
        wa_t[j * 128 + k] = s;
    }
}

// ---------------- bf16 MFMA GEMM: C[M][N] = A[M][K] @ Bt[N][K]^T ----------------
// AF32: A is fp32, converted to bf16 in-register during LDS staging.
template <bool AF32>
__global__ __launch_bounds__(256) void gnn_mfma_gemm(const void* __restrict__ Av,
                                                     const ushort* __restrict__ Bt,
                                                     ushort* __restrict__ C,
                                                     int M, int N, int K) {
    __shared__ ushort As[64 * 40];
    __shared__ ushort Bs[64 * 40];
    const int tid = threadIdx.x;
    const int wv = tid >> 6, lane = tid & 63;
    const int g = lane >> 4, r = lane & 15;
    const int brow = blockIdx.y << 6, bcol = blockIdx.x << 6;

    const int srow = tid >> 2;
    const int skoff = (tid & 3) << 3;
    int arow = brow + srow;
    if (arow >= M) arow = M - 1;
    const ushort* A16 = (const ushort*)Av;
    const float*  A32 = (const float*)Av;
    const ushort* Ap16 = A16 + (size_t)arow * K + skoff;
    const float*  Ap32 = A32 + (size_t)arow * K + skoff;
    const ushort* Bp = Bt + (size_t)(bcol + srow) * K + skoff;
    ushort* AsW = &As[srow * 40 + skoff];
    ushort* BsW = &Bs[srow * 40 + skoff];

    f32x4 acc[4] = {};

    for (int k0 = 0; k0 < K; k0 += 32) {
        if constexpr (AF32) {
            float4 f0 = *(const float4*)(Ap32 + k0);
            float4 f1 = *(const float4*)(Ap32 + k0 + 4);
            short8 t;
            t[0] = (short)f2b(f0.x); t[1] = (short)f2b(f0.y);
            t[2] = (short)f2b(f0.z); t[3] = (short)f2b(f0.w);
            t[4] = (short)f2b(f1.x); t[5] = (short)f2b(f1.y);
            t[6] = (short)f2b(f1.z); t[7] = (short)f2b(f1.w);
            *(short8*)AsW = t;
        } else {
            *(short8*)AsW = *(const short8*)(Ap16 + k0);
        }
        *(short8*)BsW = *(const short8*)(Bp + k0);
        __syncthreads();
        short8 bfrag = *(const short8*)&Bs[(wv * 16 + r) * 40 + g * 8];
#pragma unroll
        for (int mb = 0; mb < 4; ++mb) {
            short8 afrag = *(const short8*)&As[(mb * 16 + r) * 40 + g * 8];
            acc[mb] = __builtin_amdgcn_mfma_f32_16x16x32_bf16(afrag, bfrag, acc[mb], 0, 0, 0);
        }
        __syncthreads();
    }

    const int col = bcol + wv * 16 + r;
#pragma unroll
    for (int mb = 0; mb < 4; ++mb) {
        int rowb = brow + mb * 16 + g * 4;
#pragma unroll
        for (int rr = 0; rr < 4; ++rr) {
            int row = rowb + rr;
            if (row < M) C[(size_t)row * N + col] = f2b(acc[mb][rr]);
        }
    }
}

// ------- GCN1 gather + fused bias/relu + fused attention dots (asd), 8-deep MLP -------
__global__ __launch_bounds__(256) void gnn_gcn_node128_asd(const int* __restrict__ row_ptr,
                                                           const int* __restrict__ esrc,
                                                           const float* __restrict__ ecw,
                                                           const float* __restrict__ dinv,
                                                           const ushort* __restrict__ hb,
                                                           const float* __restrict__ b,
                                                           const float* __restrict__ wa,
                                                           ushort* __restrict__ out,
                                                           float* __restrict__ a_s,
                                                           float* __restrict__ a_d, int n) {
    __shared__ float swa[16 * 128];
    for (int i = threadIdx.x; i < 16 * 128; i += 256) swa[i] = wa[i];
    __syncthreads();
    int v = blockIdx.x * 4 + (threadIdx.x >> 6);
    int lane = threadIdx.x & 63;
    if (v >= n) return;
    float di = dinv[v];
    float sc = di * di;
    uint us = *(const uint*)(hb + (size_t)v * 128 + 2 * lane);
    float acc0 = sc * __uint_as_float(us << 16);
    float acc1 = sc * __uint_as_float(us & 0xffff0000u);
    int beg = row_ptr[v], end = row_ptr[v + 1];
    int p = beg;
    for (; p + 8 <= end; p += 8) {
        int s[8]; float c[8]; uint u[8];
#pragma unroll
        for (int t = 0; t < 8; ++t) s[t] = esrc[p + t];
#pragma unroll
        for (int t = 0; t < 8; ++t) c[t] = ecw[p + t];
#pragma unroll
        for (int t = 0; t < 8; ++t) u[t] = *(const uint*)(hb + (size_t)s[t] * 128 + 2 * lane);
#pragma unroll
        for (int t = 0; t < 8; ++t) {
            acc0 += c[t] * __uint_as_float(u[t] << 16);
            acc1 += c[t] * __uint_as_float(u[t] & 0xffff0000u);
        }
    }
    for (; p < end; ++p) {
        int s = esrc[p];
        float cw = ecw[p];
        uint u = *(const uint*)(hb + (size_t)s * 128 + 2 * lane);
        acc0 += cw * __uint_as_float(u << 16);
        acc1 += cw * __uint_as_float(u & 0xffff0000u);
    }
    float o0 = acc0 + b[2 * lane];
    float o1 = acc1 + b[2 * lane + 1];
    o0 = o0 > 0.f ? o0 : 0.f;
    o1 = o1 > 0.f ? o1 : 0.f;
    uint o = (uint)f2b(o0) | ((uint)f2b(o1) << 16);
    *(uint*)(out + (size_t)v * 128 + 2 * lane) = o;

    // fused a_s/a_d: dot(g1 row, wa[j]) for j=0..15
    float part[16];
#pragma unroll
    for (int j = 0; j < 16; ++j)
        part[j] = o0 * swa[j * 128 + 2 * lane] + o1 * swa[j * 128 + 2 * lane + 1];
#pragma unroll
    for (int m = 1; m < 64; m <<= 1) {
#pragma unroll
        for (int j = 0; j < 16; ++j) part[j] += __shfl_xor(part[j], m);
    }
    if (lane == 0) {
#pragma unroll
        for (int j = 0; j < 8; ++j) {
            a_s[(size_t)v * 8 + j] = part[j];
            a_d[(size_t)v * 8 + j] = part[8 + j];
        }
    }
}

// ------- GAT per-node: fused softmax+gather; lane = (head L>>3, chan-block L&7); 8-deep MLP -------
__global__ __launch_bounds__(256) void gnn_gat_node2(const int* __restrict__ row_ptr,
                                                     const int* __restrict__ esrc,
                                                     const float* __restrict__ a_s,
                                                     const float* __restrict__ a_d,
                                                     const ushort* __restrict__ h2,
                                                     const float* __restrict__ gat_b,
                                                     ushort* __restrict__ out, int n) {
    int v = blockIdx.x * 4 + (threadIdx.x >> 6);
    int lane = threadIdx.x & 63;
    if (v >= n) return;
    const int hd = lane >> 3;
    const float adh = a_d[(size_t)v * 8 + hd];

    float vh[8];
    float sl;
    {   // self edge
        float ps = __expf(leaky02(a_s[(size_t)v * 8 + hd] + adh));
        short8 q = *(const short8*)(h2 + (size_t)v * 512 + lane * 8);
        sl = ps;
#pragma unroll
        for (int j = 0; j < 8; ++j) vh[j] = ps * b2f((ushort)q[j]);
    }
    int beg = row_ptr[v], end = row_ptr[v + 1];
    int p = beg;
    for (; p + 8 <= end; p += 8) {
        int s[8]; float e[8]; short8 q[8];
#pragma unroll
        for (int t = 0; t < 8; ++t) s[t] = esrc[p + t];
#pragma unroll
        for (int t = 0; t < 8; ++t) e[t] = a_s[(size_t)s[t] * 8 + hd];
#pragma unroll
        for (int t = 0; t < 8; ++t) q[t] = *(const short8*)(h2 + (size_t)s[t] * 512 + lane * 8);
#pragma unroll
        for (int t = 0; t < 8; ++t) {
            float pp = __expf(leaky02(e[t] + adh));
            sl += pp;
#pragma unroll
            for (int j = 0; j < 8; ++j) vh[j] += pp * b2f((ushort)q[t][j]);
        }
    }
    if (p + 4 <= end) {
        int s[4]; float e[4]; short8 q[4];
#pragma unroll
        for (int t = 0; t < 4; ++t) s[t] = esrc[p + t];
#pragma unroll
        for (int t = 0; t < 4; ++t) e[t] = a_s[(size_t)s[t] * 8 + hd];
#pragma unroll
        for (int t = 0; t < 4; ++t) q[t] = *(const short8*)(h2 + (size_t)s[t] * 512 + lane * 8);
#pragma unroll
        for (int t = 0; t < 4; ++t) {
            float pp = __expf(leaky02(e[t] + adh));
            sl += pp;
#pragma unroll
            for (int j = 0; j < 8; ++j) vh[j] += pp * b2f((ushort)q[t][j]);
        }
        p += 4;
    }
    for (; p < end; ++p) {
        int s = esrc[p];
        float pp = __expf(leaky02(a_s[(size_t)s * 8 + hd] + adh));
        short8 q = *(const short8*)(h2 + (size_t)s * 512 + lane * 8);
        sl += pp;
#pragma unroll
        for (int j = 0; j < 8; ++j) vh[j] += pp * b2f((ushort)q[j]);
    }
    float rs = 1.f / (sl + 1e-16f);
#pragma unroll
    for (int j = 0; j < 8; ++j) vh[j] *= rs;
    // mean over heads: reduce across lane bits 3,4,5
#pragma unroll
    for (int m = 8; m < 64; m <<= 1) {
#pragma unroll
        for (int j = 0; j < 8; ++j) vh[j] += __shfl_xor(vh[j], m);
    }
    if (lane < 8) {
        short8 o;
#pragma unroll
        for (int j = 0; j < 8; ++j) {
            float t = 0.125f * vh[j] + gat_b[lane * 8 + j];
            t = t > 0.f ? t : 0.f;
            o[j] = (short)f2b(t);
        }
        *(short8*)(out + (size_t)v * 64 + lane * 8) = o;
    }
}

// ---------------- GCN2 per-node gather + fused FC -> d_out; 8-deep MLP ----------------
__global__ __launch_bounds__(256) void gnn_gcn_node64_fc(const int* __restrict__ row_ptr,
                                                         const int* __restrict__ esrc,
                                                         const float* __restrict__ ecw,
                                                         const float* __restrict__ dinv,
                                                         const ushort* __restrict__ hb,
                                                         const float* __restrict__ b,
                                                         const float* __restrict__ fc_w,
                                                         const float* __restrict__ fc_b,
                                                         float* __restrict__ out, int n) {
    int v = blockIdx.x * 4 + (threadIdx.x >> 6);
    int lane = threadIdx.x & 63;
    if (v >= n) return;
    float di = dinv[v];
    float acc = di * di * b2f(hb[(size_t)v * 64 + lane]);
    int beg = row_ptr[v], end = row_ptr[v + 1];
    int p = beg;
    for (; p + 8 <= end; p += 8) {
        int s[8]; float c[8]; ushort hv[8];
#pragma unroll
        for (int t = 0; t < 8; ++t) s[t] = esrc[p + t];
#pragma unroll
        for (int t = 0; t < 8; ++t) c[t] = ecw[p + t];
#pragma unroll
        for (int t = 0; t < 8; ++t) hv[t] = hb[(size_t)s[t] * 64 + lane];
#pragma unroll
        for (int t = 0; t < 8; ++t) acc += c[t] * b2f(hv[t]);
    }
    for (; p < end; ++p) {
        int s = esrc[p];
        acc += ecw[p] * b2f(hb[(size_t)s * 64 + lane]);
    }
    float o = acc + b[lane];
    o = o > 0.f ? o : 0.f;
    float val = o * fc_w[lane];
#pragma unroll
    for (int m = 32; m; m >>= 1) val += __shfl_xor(val, m);
    if (lane == 0) out[v] = val + fc_b[0];
}

// ---------------- launch ----------------
extern "C" void kernel_launch(void* const* d_in, const int* in_sizes, int n_in,
                              void* d_out, int out_size, void* d_ws, size_t ws_size,
                              hipStream_t stream) {
    const float* x       = (const float*)d_in[0];
    const int*   ei      = (const int*)d_in[1];
    const float* ew      = (const float*)d_in[2];
    const float* gc1_w   = (const float*)d_in[3];
    const float* gc1_b   = (const float*)d_in[4];
    const float* gat_w   = (const float*)d_in[5];
    const float* att_src = (const float*)d_in[6];
    const float* att_dst = (const float*)d_in[7];
    const float* gat_b   = (const float*)d_in[8];
    const float* gc2_w   = (const float*)d_in[9];
    const float* gc2_b   = (const float*)d_in[10];
    const float* fc_w    = (const float*)d_in[11];
    const float* fc_b    = (const float*)d_in[12];
    float* out = (float*)d_out;

    const int N = GNN_N;
    const int E = in_sizes[2];
    const int* src = ei;
    const int* dst = ei + E;

    // ---- workspace layout (~100 MB) ----
    char* p = (char*)d_ws;
    ushort* h2b = (ushort*)p; p += (size_t)N * 512 * 2;   // 51.2 MB
    ushort* h1b = (ushort*)p; p += (size_t)N * 128 * 2;   // 12.8 MB
    ushort* g1b = (ushort*)p; p += (size_t)N * 128 * 2;   // 12.8 MB
    ushort* g2b = (ushort*)p; p += (size_t)N * 64 * 2;    // 6.4 MB
    ushort* h3b = (ushort*)p; p += (size_t)N * 64 * 2;    // 6.4 MB
    ushort* w1t = (ushort*)p; p += (size_t)128 * 256 * 2; // 64 KB
    ushort* w2t = (ushort*)p; p += (size_t)512 * 128 * 2; // 128 KB
    ushort* w3t = (ushort*)p; p += (size_t)64 * 64 * 2;   // 8 KB
    float*  wa_t = (float*)p; p += 16 * 128 * 4;          // 8 KB
    float*  a_s = (float*)p;  p += (size_t)N * 8 * 4;
    float*  a_d = (float*)p;  p += (size_t)N * 8 * 4;
    int* row_ptr = (int*)p;   p += (size_t)(N + 64) * 4;
    int* esrc = (int*)p;      p += (size_t)E * 4;
    float* ecw = (float*)p;   p += (size_t)E * 4;
    // contiguous for single memset: cnt, fill, dinv
    int* cnt = (int*)p;       p += (size_t)N * 4;
    int* fill = (int*)p;      p += (size_t)N * 4;
    float* dinv = (float*)p;  p += (size_t)N * 4;
    int* blksum = (int*)p;    p += 4096;

    auto cdiv = [](long a, long b) { return (int)((a + b - 1) / b); };

    // ---- CSR build + symmetric norm ----
    hipMemsetAsync(cnt, 0, (size_t)N * 12, stream);  // cnt + fill + dinv(acc)
    gnn_hist<<<cdiv(E, 256), 256, 0, stream>>>(dst, ew, cnt, dinv, E);
    gnn_deg_fin<<<cdiv(N, 256), 256, 0, stream>>>(dinv, N);
    const int nblk = cdiv(N, 1024);
    gnn_scan1<<<nblk, 256, 0, stream>>>(cnt, row_ptr, blksum, N);
    gnn_scan2<<<1, 64, 0, stream>>>(blksum, nblk, row_ptr + N, E);
    gnn_scan3<<<cdiv(N, 256), 256, 0, stream>>>(row_ptr, blksum, N);
    gnn_scatter<<<cdiv(E, 256), 256, 0, stream>>>(src, dst, ew, dinv, row_ptr, fill, esrc, ecw, E);

    // ---- fused prep (weight transposes + att fold): 408 blocks ----
    gnn_prep<<<408, 256, 0, stream>>>(gc1_w, gat_w, gc2_w, att_src, att_dst, w1t, w2t, w3t, wa_t);

    // ---- GCN1: h1b = bf16(x @ gc1_w) [MFMA, fp32-A]; gather + fused asd ----
    {
        dim3 grid(128 / 64, cdiv(N, 64));
        gnn_mfma_gemm<true><<<grid, 256, 0, stream>>>(x, w1t, h1b, N, 128, 256);
    }
    gnn_gcn_node128_asd<<<cdiv(N, 4), 256, 0, stream>>>(row_ptr, esrc, ecw, dinv, h1b, gc1_b,
                                                        wa_t, g1b, a_s, a_d, N);

    // ---- GAT ----
    {
        dim3 grid(512 / 64, cdiv(N, 64));
        gnn_mfma_gemm<false><<<grid, 256, 0, stream>>>(g1b, w2t, h2b, N, 512, 128);
    }
    gnn_gat_node2<<<cdiv(N, 4), 256, 0, stream>>>(row_ptr, esrc, a_s, a_d, h2b, gat_b, g2b, N);

    // ---- GCN2 + FC ----
    {
        dim3 grid(1, cdiv(N, 64));
        gnn_mfma_gemm<false><<<grid, 256, 0, stream>>>(g2b, w3t, h3b, N, 64, 64);
    }
    gnn_gcn_node64_fc<<<cdiv(N, 4), 256, 0, stream>>>(row_ptr, esrc, ecw, dinv, h3b, gc2_b,
                                                      fc_w, fc_b, out, N);
}

// Round 9
// 348.070 us; speedup vs baseline: 1.3931x; 1.0771x over previous
//
#include <hip/hip_runtime.h>
#include <hip/hip_bf16.h>

#define GNN_N 50000
#define GNN_E 600000

typedef unsigned int uint;
typedef unsigned short ushort;
using short8 = __attribute__((ext_vector_type(8))) short;
using f32x4  = __attribute__((ext_vector_type(4))) float;

__device__ __forceinline__ float leaky02(float x) { return x > 0.f ? x : 0.2f * x; }
__device__ __forceinline__ ushort f2b(float f) {  // RNE float->bf16
    uint u = __float_as_uint(f);
    return (ushort)((u + 0x7fffu + ((u >> 16) & 1u)) >> 16);
}
__device__ __forceinline__ float b2f(ushort b) { return __uint_as_float(((uint)b) << 16); }

// ---------------- degree / CSR build ----------------
__global__ void gnn_hist(const int* __restrict__ dst, const float* __restrict__ ew,
                         int* __restrict__ cnt, float* __restrict__ deg, int e) {
    int i = blockIdx.x * blockDim.x + threadIdx.x;
    if (i >= e) return;
    int d = dst[i];
    atomicAdd(&cnt[d], 1);
    atomicAdd(&deg[d], ew[i]);
}
__global__ void gnn_deg_fin(float* deg, int n) {
    int i = blockIdx.x * blockDim.x + threadIdx.x;
    if (i < n) deg[i] = rsqrtf(1.0f + deg[i]);
}
__global__ void gnn_scan1(const int* __restrict__ cnt, int* __restrict__ row_ptr,
                          int* __restrict__ blksum, int n) {
    __shared__ int sh[256];
    int tid = threadIdx.x;
    int base = blockIdx.x * 1024 + tid * 4;
    int v0 = (base + 0 < n) ? cnt[base + 0] : 0;
    int v1 = (base + 1 < n) ? cnt[base + 1] : 0;
    int v2 = (base + 2 < n) ? cnt[base + 2] : 0;
    int v3 = (base + 3 < n) ? cnt[base + 3] : 0;
    int tsum = v0 + v1 + v2 + v3;
    sh[tid] = tsum;
    __syncthreads();
    for (int off = 1; off < 256; off <<= 1) {
        int t = (tid >= off) ? sh[tid - off] : 0;
        __syncthreads();
        sh[tid] += t;
        __syncthreads();
    }
    int excl = sh[tid] - tsum;
    if (base + 0 < n) row_ptr[base + 0] = excl; excl += v0;
    if (base + 1 < n) row_ptr[base + 1] = excl; excl += v1;
    if (base + 2 < n) row_ptr[base + 2] = excl; excl += v2;
    if (base + 3 < n) row_ptr[base + 3] = excl;
    if (tid == 255) blksum[blockIdx.x] = sh[255];
}
__global__ void gnn_scan2(int* blksum, int nblk, int* row_ptr_end, int total) {
    if (threadIdx.x == 0 && blockIdx.x == 0) {
        int run = 0;
        for (int b = 0; b < nblk; ++b) { int t = blksum[b]; blksum[b] = run; run += t; }
        *row_ptr_end = total;
    }
}
__global__ void gnn_scan3(int* row_ptr, const int* __restrict__ blksum, int n) {
    int i = blockIdx.x * blockDim.x + threadIdx.x;
    if (i < n) row_ptr[i] += blksum[i >> 10];
}
__global__ void gnn_scatter(const int* __restrict__ src, const int* __restrict__ dst,
                            const float* __restrict__ ew, const float* __restrict__ dinv,
                            const int* __restrict__ row_ptr, int* __restrict__ fill,
                            int* __restrict__ esrc, float* __restrict__ ecw, int e) {
    int i = blockIdx.x * blockDim.x + threadIdx.x;
    if (i >= e) return;
    int d = dst[i];
    int s = src[i];
    int pos = row_ptr[d] + atomicAdd(&fill[d], 1);
    esrc[pos] = s;
    ecw[pos] = dinv[s] * ew[i] * dinv[d];
}

// ---------------- fused prep: weight transposes/folds ----------------
// w1t[128][256] <- gc1_w[256][128]; w2s_t[64][1024] <- 0.125*gat_w (head-stacked);
// w3t[64][64] <- gc2_w; wa_t[16][128] <- att fold.
__global__ void gnn_prep(const float* __restrict__ gc1_w, const float* __restrict__ gat_w,
                         const float* __restrict__ gc2_w, const float* __restrict__ att_src,
                         const float* __restrict__ att_dst, ushort* __restrict__ w1t,
                         ushort* __restrict__ w2s_t, ushort* __restrict__ w3t,
                         float* __restrict__ wa_t) {
    int t = blockIdx.x * 256 + threadIdx.x;
    if (t < 32768) {                       // gc1_w [256][128] -> w1t[128][256]
        int k = t >> 7, n = t & 127;
        w1t[n * 256 + k] = f2b(gc1_w[t]);
        return;
    }
    t -= 32768;
    if (t < 65536) {                       // w2s_t[c][h*128+k] = gat_w[k][h*64+c]/8
        int c = t >> 10, r = t & 1023;
        int h = r >> 7, k = r & 127;
        w2s_t[t] = f2b(0.125f * gat_w[(size_t)k * 512 + h * 64 + c]);
        return;
    }
    t -= 65536;
    if (t < 4096) {                        // gc2_w [64][64] -> w3t[64][64]
        int k = t >> 6, n = t & 63;
        w3t[n * 64 + k] = f2b(gc2_w[t]);
        return;
    }
    t -= 4096;
    if (t < 2048) {                        // wa_t[16][128]: fold att into weight space
        int j = t >> 7, k = t & 127;
        int h = j & 7;
        const float* av = (j < 8) ? att_src : att_dst;
        float s = 0.f;
        for (int c = 0; c < 64; ++c) s += gat_w[(size_t)k * 512 + h * 64 + c] * av[h * 64 + c];
        wa_t[j * 128 + k] = s;
    }
}

// ---------------- bf16 MFMA GEMM: C[M][N] = A[M][K] @ Bt[N][K]^T ----------------
// AF32: A fp32, cast during staging. BIAS: fused +bias & relu epilogue.
template <bool AF32, bool BIAS>
__global__ __launch_bounds__(256) void gnn_mfma_gemm(const void* __restrict__ Av,
                                                     const ushort* __restrict__ Bt,
                                                     ushort* __restrict__ C,
                                                     const float* __restrict__ bias,
                                                     int M, int N, int K) {
    __shared__ ushort As[64 * 40];
    __shared__ ushort Bs[64 * 40];
    const int tid = threadIdx.x;
    const int wv = tid >> 6, lane = tid & 63;
    const int g = lane >> 4, r = lane & 15;
    const int brow = blockIdx.y << 6, bcol = blockIdx.x << 6;

    const int srow = tid >> 2;
    const int skoff = (tid & 3) << 3;
    int arow = brow + srow;
    if (arow >= M) arow = M - 1;
    const ushort* A16 = (const ushort*)Av;
    const float*  A32 = (const float*)Av;
    const ushort* Ap16 = A16 + (size_t)arow * K + skoff;
    const float*  Ap32 = A32 + (size_t)arow * K + skoff;
    const ushort* Bp = Bt + (size_t)(bcol + srow) * K + skoff;
    ushort* AsW = &As[srow * 40 + skoff];
    ushort* BsW = &Bs[srow * 40 + skoff];

    f32x4 acc[4] = {};

    for (int k0 = 0; k0 < K; k0 += 32) {
        if constexpr (AF32) {
            float4 f0 = *(const float4*)(Ap32 + k0);
            float4 f1 = *(const float4*)(Ap32 + k0 + 4);
            short8 t;
            t[0] = (short)f2b(f0.x); t[1] = (short)f2b(f0.y);
            t[2] = (short)f2b(f0.z); t[3] = (short)f2b(f0.w);
            t[4] = (short)f2b(f1.x); t[5] = (short)f2b(f1.y);
            t[6] = (short)f2b(f1.z); t[7] = (short)f2b(f1.w);
            *(short8*)AsW = t;
        } else {
            *(short8*)AsW = *(const short8*)(Ap16 + k0);
        }
        *(short8*)BsW = *(const short8*)(Bp + k0);
        __syncthreads();
        short8 bfrag = *(const short8*)&Bs[(wv * 16 + r) * 40 + g * 8];
#pragma unroll
        for (int mb = 0; mb < 4; ++mb) {
            short8 afrag = *(const short8*)&As[(mb * 16 + r) * 40 + g * 8];
            acc[mb] = __builtin_amdgcn_mfma_f32_16x16x32_bf16(afrag, bfrag, acc[mb], 0, 0, 0);
        }
        __syncthreads();
    }

    const int col = bcol + wv * 16 + r;
    float bv = 0.f;
    if constexpr (BIAS) bv = bias[col];
#pragma unroll
    for (int mb = 0; mb < 4; ++mb) {
        int rowb = brow + mb * 16 + g * 4;
#pragma unroll
        for (int rr = 0; rr < 4; ++rr) {
            int row = rowb + rr;
            if (row < M) {
                float val = acc[mb][rr];
                if constexpr (BIAS) {
                    val += bv;
                    val = val > 0.f ? val : 0.f;
                }
                C[(size_t)row * N + col] = f2b(val);
            }
        }
    }
}

// ------- GCN1 gather + fused bias/relu + fused attention dots (asd), 8-deep MLP -------
__global__ __launch_bounds__(256) void gnn_gcn_node128_asd(const int* __restrict__ row_ptr,
                                                           const int* __restrict__ esrc,
                                                           const float* __restrict__ ecw,
                                                           const float* __restrict__ dinv,
                                                           const ushort* __restrict__ hb,
                                                           const float* __restrict__ b,
                                                           const float* __restrict__ wa,
                                                           ushort* __restrict__ out,
                                                           float* __restrict__ a_s,
                                                           float* __restrict__ a_d, int n) {
    __shared__ float swa[16 * 128];
    for (int i = threadIdx.x; i < 16 * 128; i += 256) swa[i] = wa[i];
    __syncthreads();
    int v = blockIdx.x * 4 + (threadIdx.x >> 6);
    int lane = threadIdx.x & 63;
    if (v >= n) return;
    float di = dinv[v];
    float sc = di * di;
    uint us = *(const uint*)(hb + (size_t)v * 128 + 2 * lane);
    float acc0 = sc * __uint_as_float(us << 16);
    float acc1 = sc * __uint_as_float(us & 0xffff0000u);
    int beg = row_ptr[v], end = row_ptr[v + 1];
    int p = beg;
    for (; p + 8 <= end; p += 8) {
        int s[8]; float c[8]; uint u[8];
#pragma unroll
        for (int t = 0; t < 8; ++t) s[t] = esrc[p + t];
#pragma unroll
        for (int t = 0; t < 8; ++t) c[t] = ecw[p + t];
#pragma unroll
        for (int t = 0; t < 8; ++t) u[t] = *(const uint*)(hb + (size_t)s[t] * 128 + 2 * lane);
#pragma unroll
        for (int t = 0; t < 8; ++t) {
            acc0 += c[t] * __uint_as_float(u[t] << 16);
            acc1 += c[t] * __uint_as_float(u[t] & 0xffff0000u);
        }
    }
    for (; p < end; ++p) {
        int s = esrc[p];
        float cw = ecw[p];
        uint u = *(const uint*)(hb + (size_t)s * 128 + 2 * lane);
        acc0 += cw * __uint_as_float(u << 16);
        acc1 += cw * __uint_as_float(u & 0xffff0000u);
    }
    float o0 = acc0 + b[2 * lane];
    float o1 = acc1 + b[2 * lane + 1];
    o0 = o0 > 0.f ? o0 : 0.f;
    o1 = o1 > 0.f ? o1 : 0.f;
    uint o = (uint)f2b(o0) | ((uint)f2b(o1) << 16);
    *(uint*)(out + (size_t)v * 128 + 2 * lane) = o;

    float part[16];
#pragma unroll
    for (int j = 0; j < 16; ++j)
        part[j] = o0 * swa[j * 128 + 2 * lane] + o1 * swa[j * 128 + 2 * lane + 1];
#pragma unroll
    for (int m = 1; m < 64; m <<= 1) {
#pragma unroll
        for (int j = 0; j < 16; ++j) part[j] += __shfl_xor(part[j], m);
    }
    if (lane == 0) {
#pragma unroll
        for (int j = 0; j < 8; ++j) {
            a_s[(size_t)v * 8 + j] = part[j];
            a_d[(size_t)v * 8 + j] = part[8 + j];
        }
    }
}

// ------- GAT z-space aggregation: z_h[v] = (1/S_vh) Σ_s p_sh g1[s]  (128-dim gather) -------
// lane owns channels 2L,2L+1 for all 8 heads; lane computes head (L&7)'s exp, shfl-broadcast.
__global__ __launch_bounds__(256) void gnn_gat_z(const int* __restrict__ row_ptr,
                                                 const int* __restrict__ esrc,
                                                 const float* __restrict__ a_s,
                                                 const float* __restrict__ a_d,
                                                 const ushort* __restrict__ g1b,
                                                 ushort* __restrict__ zb, int n) {
    int v = blockIdx.x * 4 + (threadIdx.x >> 6);
    int lane = threadIdx.x & 63;
    if (v >= n) return;
    const int hh = lane & 7;
    const float adh = a_d[(size_t)v * 8 + hh];

    float z0[8] = {}, z1[8] = {};
    float sl;
    {   // self edge
        float pv = __expf(leaky02(a_s[(size_t)v * 8 + hh] + adh));
        uint u = *(const uint*)(g1b + (size_t)v * 128 + 2 * lane);
        float g0 = __uint_as_float(u << 16);
        float g1v = __uint_as_float(u & 0xffff0000u);
        sl = pv;
        float ph[8];
#pragma unroll
        for (int h = 0; h < 8; ++h) ph[h] = __shfl(pv, h);
#pragma unroll
        for (int h = 0; h < 8; ++h) { z0[h] += ph[h] * g0; z1[h] += ph[h] * g1v; }
    }
    int beg = row_ptr[v], end = row_ptr[v + 1];
    int p = beg;
    for (; p + 4 <= end; p += 4) {
        int s[4]; float e[4]; uint u[4];
#pragma unroll
        for (int t = 0; t < 4; ++t) s[t] = esrc[p + t];
#pragma unroll
        for (int t = 0; t < 4; ++t) e[t] = a_s[(size_t)s[t] * 8 + hh];
#pragma unroll
        for (int t = 0; t < 4; ++t) u[t] = *(const uint*)(g1b + (size_t)s[t] * 128 + 2 * lane);
#pragma unroll
        for (int t = 0; t < 4; ++t) {
            float pv = __expf(leaky02(e[t] + adh));
            sl += pv;
            float g0 = __uint_as_float(u[t] << 16);
            float g1v = __uint_as_float(u[t] & 0xffff0000u);
            float ph[8];
#pragma unroll
            for (int h = 0; h < 8; ++h) ph[h] = __shfl(pv, h);
#pragma unroll
            for (int h = 0; h < 8; ++h) { z0[h] += ph[h] * g0; z1[h] += ph[h] * g1v; }
        }
    }
    for (; p < end; ++p) {
        int s = esrc[p];
        float pv = __expf(leaky02(a_s[(size_t)s * 8 + hh] + adh));
        uint u = *(const uint*)(g1b + (size_t)s * 128 + 2 * lane);
        sl += pv;
        float g0 = __uint_as_float(u << 16);
        float g1v = __uint_as_float(u & 0xffff0000u);
        float ph[8];
#pragma unroll
        for (int h = 0; h < 8; ++h) ph[h] = __shfl(pv, h);
#pragma unroll
        for (int h = 0; h < 8; ++h) { z0[h] += ph[h] * g0; z1[h] += ph[h] * g1v; }
    }
    // per-head sums: lane h holds S_h (identical across lanes with same lane&7)
    float slx = sl + 1e-16f;
#pragma unroll
    for (int h = 0; h < 8; ++h) {
        float rs = 1.f / __shfl(slx, h);
        uint o = (uint)f2b(z0[h] * rs) | ((uint)f2b(z1[h] * rs) << 16);
        *(uint*)(zb + (size_t)v * 1024 + h * 128 + 2 * lane) = o;
    }
}

// ---------------- GCN2 per-node gather + fused FC -> d_out; 8-deep MLP ----------------
__global__ __launch_bounds__(256) void gnn_gcn_node64_fc(const int* __restrict__ row_ptr,
                                                         const int* __restrict__ esrc,
                                                         const float* __restrict__ ecw,
                                                         const float* __restrict__ dinv,
                                                         const ushort* __restrict__ hb,
                                                         const float* __restrict__ b,
                                                         const float* __restrict__ fc_w,
                                                         const float* __restrict__ fc_b,
                                                         float* __restrict__ out, int n) {
    int v = blockIdx.x * 4 + (threadIdx.x >> 6);
    int lane = threadIdx.x & 63;
    if (v >= n) return;
    float di = dinv[v];
    float acc = di * di * b2f(hb[(size_t)v * 64 + lane]);
    int beg = row_ptr[v], end = row_ptr[v + 1];
    int p = beg;
    for (; p + 8 <= end; p += 8) {
        int s[8]; float c[8]; ushort hv[8];
#pragma unroll
        for (int t = 0; t < 8; ++t) s[t] = esrc[p + t];
#pragma unroll
        for (int t = 0; t < 8; ++t) c[t] = ecw[p + t];
#pragma unroll
        for (int t = 0; t < 8; ++t) hv[t] = hb[(size_t)s[t] * 64 + lane];
#pragma unroll
        for (int t = 0; t < 8; ++t) acc += c[t] * b2f(hv[t]);
    }
    for (; p < end; ++p) {
        int s = esrc[p];
        acc += ecw[p] * b2f(hb[(size_t)s * 64 + lane]);
    }
    float o = acc + b[lane];
    o = o > 0.f ? o : 0.f;
    float val = o * fc_w[lane];
#pragma unroll
    for (int m = 32; m; m >>= 1) val += __shfl_xor(val, m);
    if (lane == 0) out[v] = val + fc_b[0];
}

// ---------------- launch ----------------
extern "C" void kernel_launch(void* const* d_in, const int* in_sizes, int n_in,
                              void* d_out, int out_size, void* d_ws, size_t ws_size,
                              hipStream_t stream) {
    const float* x       = (const float*)d_in[0];
    const int*   ei      = (const int*)d_in[1];
    const float* ew      = (const float*)d_in[2];
    const float* gc1_w   = (const float*)d_in[3];
    const float* gc1_b   = (const float*)d_in[4];
    const float* gat_w   = (const float*)d_in[5];
    const float* att_src = (const float*)d_in[6];
    const float* att_dst = (const float*)d_in[7];
    const float* gat_b   = (const float*)d_in[8];
    const float* gc2_w   = (const float*)d_in[9];
    const float* gc2_b   = (const float*)d_in[10];
    const float* fc_w    = (const float*)d_in[11];
    const float* fc_b    = (const float*)d_in[12];
    float* out = (float*)d_out;

    const int N = GNN_N;
    const int E = in_sizes[2];
    const int* src = ei;
    const int* dst = ei + E;

    // ---- workspace layout (~150 MB) ----
    char* p = (char*)d_ws;
    ushort* zb  = (ushort*)p; p += (size_t)N * 1024 * 2;  // 102.4 MB [N][8*128] bf16
    ushort* h1b = (ushort*)p; p += (size_t)N * 128 * 2;   // 12.8 MB
    ushort* g1b = (ushort*)p; p += (size_t)N * 128 * 2;   // 12.8 MB
    ushort* g2b = (ushort*)p; p += (size_t)N * 64 * 2;    // 6.4 MB
    ushort* h3b = (ushort*)p; p += (size_t)N * 64 * 2;    // 6.4 MB
    ushort* w1t = (ushort*)p; p += (size_t)128 * 256 * 2; // 64 KB
    ushort* w2s_t = (ushort*)p; p += (size_t)64 * 1024 * 2; // 128 KB
    ushort* w3t = (ushort*)p; p += (size_t)64 * 64 * 2;   // 8 KB
    float*  wa_t = (float*)p; p += 16 * 128 * 4;          // 8 KB
    float*  a_s = (float*)p;  p += (size_t)N * 8 * 4;
    float*  a_d = (float*)p;  p += (size_t)N * 8 * 4;
    int* row_ptr = (int*)p;   p += (size_t)(N + 64) * 4;
    int* esrc = (int*)p;      p += (size_t)E * 4;
    float* ecw = (float*)p;   p += (size_t)E * 4;
    int* cnt = (int*)p;       p += (size_t)N * 4;
    int* fill = (int*)p;      p += (size_t)N * 4;
    float* dinv = (float*)p;  p += (size_t)N * 4;
    int* blksum = (int*)p;    p += 4096;

    auto cdiv = [](long a, long b) { return (int)((a + b - 1) / b); };

    // ---- CSR build + symmetric norm ----
    hipMemsetAsync(cnt, 0, (size_t)N * 12, stream);  // cnt + fill + dinv(acc)
    gnn_hist<<<cdiv(E, 256), 256, 0, stream>>>(dst, ew, cnt, dinv, E);
    gnn_deg_fin<<<cdiv(N, 256), 256, 0, stream>>>(dinv, N);
    const int nblk = cdiv(N, 1024);
    gnn_scan1<<<nblk, 256, 0, stream>>>(cnt, row_ptr, blksum, N);
    gnn_scan2<<<1, 64, 0, stream>>>(blksum, nblk, row_ptr + N, E);
    gnn_scan3<<<cdiv(N, 256), 256, 0, stream>>>(row_ptr, blksum, N);
    gnn_scatter<<<cdiv(E, 256), 256, 0, stream>>>(src, dst, ew, dinv, row_ptr, fill, esrc, ecw, E);

    // ---- fused prep ----
    gnn_prep<<<408, 256, 0, stream>>>(gc1_w, gat_w, gc2_w, att_src, att_dst, w1t, w2s_t, w3t, wa_t);

    // ---- GCN1: h1b = bf16(x @ gc1_w); gather + fused asd ----
    {
        dim3 grid(128 / 64, cdiv(N, 64));
        gnn_mfma_gemm<true, false><<<grid, 256, 0, stream>>>(x, w1t, h1b, nullptr, N, 128, 256);
    }
    gnn_gcn_node128_asd<<<cdiv(N, 4), 256, 0, stream>>>(row_ptr, esrc, ecw, dinv, h1b, gc1_b,
                                                        wa_t, g1b, a_s, a_d, N);

    // ---- GAT: z-space aggregation then stacked GEMM (bias+relu fused) ----
    gnn_gat_z<<<cdiv(N, 4), 256, 0, stream>>>(row_ptr, esrc, a_s, a_d, g1b, zb, N);
    {
        dim3 grid(1, cdiv(N, 64));
        gnn_mfma_gemm<false, true><<<grid, 256, 0, stream>>>(zb, w2s_t, g2b, gat_b, N, 64, 1024);
    }

    // ---- GCN2 + FC ----
    {
        dim3 grid(1, cdiv(N, 64));
        gnn_mfma_gemm<false, false><<<grid, 256, 0, stream>>>(g2b, w3t, h3b, nullptr, N, 64, 64);
    }
    gnn_gcn_node64_fc<<<cdiv(N, 4), 256, 0, stream>>>(row_ptr, esrc, ecw, dinv, h3b, gc2_b,
                                                      fc_w, fc_b, out, N);
}

// Round 10
// 338.349 us; speedup vs baseline: 1.4332x; 1.0287x over previous
//
#include <hip/hip_runtime.h>
#include <hip/hip_bf16.h>

#define GNN_N 50000
#define GNN_E 600000

typedef unsigned int uint;
typedef unsigned short ushort;
using short8 = __attribute__((ext_vector_type(8))) short;
using f32x4  = __attribute__((ext_vector_type(4))) float;

__device__ __forceinline__ float leaky02(float x) { return x > 0.f ? x : 0.2f * x; }
__device__ __forceinline__ ushort f2b(float f) {  // RNE float->bf16
    uint u = __float_as_uint(f);
    return (ushort)((u + 0x7fffu + ((u >> 16) & 1u)) >> 16);
}
__device__ __forceinline__ float b2f(ushort b) { return __uint_as_float(((uint)b) << 16); }
__device__ __forceinline__ float blo(uint u) { return __uint_as_float(u << 16); }
__device__ __forceinline__ float bhi(uint u) { return __uint_as_float(u & 0xffff0000u); }

// ---------------- degree / CSR build ----------------
__global__ void gnn_hist(const int* __restrict__ dst, const float* __restrict__ ew,
                         int* __restrict__ cnt, float* __restrict__ deg, int e) {
    int i = blockIdx.x * blockDim.x + threadIdx.x;
    if (i >= e) return;
    int d = dst[i];
    atomicAdd(&cnt[d], 1);
    atomicAdd(&deg[d], ew[i]);
}
__global__ void gnn_deg_fin(float* deg, int n) {
    int i = blockIdx.x * blockDim.x + threadIdx.x;
    if (i < n) deg[i] = rsqrtf(1.0f + deg[i]);
}
__global__ void gnn_scan1(const int* __restrict__ cnt, int* __restrict__ row_ptr,
                          int* __restrict__ blksum, int n) {
    __shared__ int sh[256];
    int tid = threadIdx.x;
    int base = blockIdx.x * 1024 + tid * 4;
    int v0 = (base + 0 < n) ? cnt[base + 0] : 0;
    int v1 = (base + 1 < n) ? cnt[base + 1] : 0;
    int v2 = (base + 2 < n) ? cnt[base + 2] : 0;
    int v3 = (base + 3 < n) ? cnt[base + 3] : 0;
    int tsum = v0 + v1 + v2 + v3;
    sh[tid] = tsum;
    __syncthreads();
    for (int off = 1; off < 256; off <<= 1) {
        int t = (tid >= off) ? sh[tid - off] : 0;
        __syncthreads();
        sh[tid] += t;
        __syncthreads();
    }
    int excl = sh[tid] - tsum;
    if (base + 0 < n) row_ptr[base + 0] = excl; excl += v0;
    if (base + 1 < n) row_ptr[base + 1] = excl; excl += v1;
    if (base + 2 < n) row_ptr[base + 2] = excl; excl += v2;
    if (base + 3 < n) row_ptr[base + 3] = excl;
    if (tid == 255) blksum[blockIdx.x] = sh[255];
}
__global__ void gnn_scan2(int* blksum, int nblk, int* row_ptr_end, int total) {
    if (threadIdx.x == 0 && blockIdx.x == 0) {
        int run = 0;
        for (int b = 0; b < nblk; ++b) { int t = blksum[b]; blksum[b] = run; run += t; }
        *row_ptr_end = total;
    }
}
__global__ void gnn_scan3(int* row_ptr, const int* __restrict__ blksum, int n) {
    int i = blockIdx.x * blockDim.x + threadIdx.x;
    if (i < n) row_ptr[i] += blksum[i >> 10];
}
__global__ void gnn_scatter(const int* __restrict__ src, const int* __restrict__ dst,
                            const float* __restrict__ ew, const float* __restrict__ dinv,
                            const int* __restrict__ row_ptr, int* __restrict__ fill,
                            int* __restrict__ esrc, float* __restrict__ ecw, int e) {
    int i = blockIdx.x * blockDim.x + threadIdx.x;
    if (i >= e) return;
    int d = dst[i];
    int s = src[i];
    int pos = row_ptr[d] + atomicAdd(&fill[d], 1);
    esrc[pos] = s;
    ecw[pos] = dinv[s] * ew[i] * dinv[d];
}

// ---------------- fused prep: weight transposes/folds ----------------
__global__ void gnn_prep(const float* __restrict__ gc1_w, const float* __restrict__ gat_w,
                         const float* __restrict__ gc2_w, const float* __restrict__ att_src,
                         const float* __restrict__ att_dst, ushort* __restrict__ w1t,
                         ushort* __restrict__ w2s_t, ushort* __restrict__ w3t,
                         float* __restrict__ wa_t) {
    int t = blockIdx.x * 256 + threadIdx.x;
    if (t < 32768) {                       // gc1_w [256][128] -> w1t[128][256]
        int k = t >> 7, n = t & 127;
        w1t[n * 256 + k] = f2b(gc1_w[t]);
        return;
    }
    t -= 32768;
    if (t < 65536) {                       // w2s_t[c][h*128+k] = gat_w[k][h*64+c]/8
        int c = t >> 10, r = t & 1023;
        int h = r >> 7, k = r & 127;
        w2s_t[t] = f2b(0.125f * gat_w[(size_t)k * 512 + h * 64 + c]);
        return;
    }
    t -= 65536;
    if (t < 4096) {                        // gc2_w [64][64] -> w3t[64][64]
        int k = t >> 6, n = t & 63;
        w3t[n * 64 + k] = f2b(gc2_w[t]);
        return;
    }
    t -= 4096;
    if (t < 2048) {                        // wa_t[16][128]: fold att into weight space
        int j = t >> 7, k = t & 127;
        int h = j & 7;
        const float* av = (j < 8) ? att_src : att_dst;
        float s = 0.f;
        for (int c = 0; c < 64; ++c) s += gat_w[(size_t)k * 512 + h * 64 + c] * av[h * 64 + c];
        wa_t[j * 128 + k] = s;
    }
}

// ---------------- bf16 MFMA GEMM: C[M][N] = A[M][K] @ Bt[N][K]^T ----------------
template <bool AF32, bool BIAS>
__global__ __launch_bounds__(256) void gnn_mfma_gemm(const void* __restrict__ Av,
                                                     const ushort* __restrict__ Bt,
                                                     ushort* __restrict__ C,
                                                     const float* __restrict__ bias,
                                                     int M, int N, int K) {
    __shared__ ushort As[64 * 40];
    __shared__ ushort Bs[64 * 40];
    const int tid = threadIdx.x;
    const int wv = tid >> 6, lane = tid & 63;
    const int g = lane >> 4, r = lane & 15;
    const int brow = blockIdx.y << 6, bcol = blockIdx.x << 6;

    const int srow = tid >> 2;
    const int skoff = (tid & 3) << 3;
    int arow = brow + srow;
    if (arow >= M) arow = M - 1;
    const ushort* A16 = (const ushort*)Av;
    const float*  A32 = (const float*)Av;
    const ushort* Ap16 = A16 + (size_t)arow * K + skoff;
    const float*  Ap32 = A32 + (size_t)arow * K + skoff;
    const ushort* Bp = Bt + (size_t)(bcol + srow) * K + skoff;
    ushort* AsW = &As[srow * 40 + skoff];
    ushort* BsW = &Bs[srow * 40 + skoff];

    f32x4 acc[4] = {};

    for (int k0 = 0; k0 < K; k0 += 32) {
        if constexpr (AF32) {
            float4 f0 = *(const float4*)(Ap32 + k0);
            float4 f1 = *(const float4*)(Ap32 + k0 + 4);
            short8 t;
            t[0] = (short)f2b(f0.x); t[1] = (short)f2b(f0.y);
            t[2] = (short)f2b(f0.z); t[3] = (short)f2b(f0.w);
            t[4] = (short)f2b(f1.x); t[5] = (short)f2b(f1.y);
            t[6] = (short)f2b(f1.z); t[7] = (short)f2b(f1.w);
            *(short8*)AsW = t;
        } else {
            *(short8*)AsW = *(const short8*)(Ap16 + k0);
        }
        *(short8*)BsW = *(const short8*)(Bp + k0);
        __syncthreads();
        short8 bfrag = *(const short8*)&Bs[(wv * 16 + r) * 40 + g * 8];
#pragma unroll
        for (int mb = 0; mb < 4; ++mb) {
            short8 afrag = *(const short8*)&As[(mb * 16 + r) * 40 + g * 8];
            acc[mb] = __builtin_amdgcn_mfma_f32_16x16x32_bf16(afrag, bfrag, acc[mb], 0, 0, 0);
        }
        __syncthreads();
    }

    const int col = bcol + wv * 16 + r;
    float bv = 0.f;
    if constexpr (BIAS) bv = bias[col];
#pragma unroll
    for (int mb = 0; mb < 4; ++mb) {
        int rowb = brow + mb * 16 + g * 4;
#pragma unroll
        for (int rr = 0; rr < 4; ++rr) {
            int row = rowb + rr;
            if (row < M) {
                float val = acc[mb][rr];
                if constexpr (BIAS) {
                    val += bv;
                    val = val > 0.f ? val : 0.f;
                }
                C[(size_t)row * N + col] = f2b(val);
            }
        }
    }
}

// ------- GCN1 gather + bias/relu + fused asd. Half-wave edge pairing:
// lane = (half = lane>>5, sl = lane&31); lane owns channels 4sl..4sl+3 (uint2). -------
__global__ __launch_bounds__(256) void gnn_gcn_node128_asd(const int* __restrict__ row_ptr,
                                                           const int* __restrict__ esrc,
                                                           const float* __restrict__ ecw,
                                                           const float* __restrict__ dinv,
                                                           const ushort* __restrict__ hb,
                                                           const float* __restrict__ b,
                                                           const float* __restrict__ wa,
                                                           ushort* __restrict__ out,
                                                           float* __restrict__ a_s,
                                                           float* __restrict__ a_d, int n) {
    __shared__ float swa[16 * 128];
    for (int i = threadIdx.x; i < 16 * 128; i += 256) swa[i] = wa[i];
    __syncthreads();
    int v = blockIdx.x * 4 + (threadIdx.x >> 6);
    int lane = threadIdx.x & 63;
    if (v >= n) return;
    const int sl = lane & 31;
    const int half = lane >> 5;
    float di = dinv[v];
    float a0, a1, a2, a3;
    {   // self (half 0 only; half 1 scaled by 0)
        float scl = half ? 0.f : di * di;
        uint2 u = *(const uint2*)(hb + (size_t)v * 128 + 4 * sl);
        a0 = scl * blo(u.x); a1 = scl * bhi(u.x);
        a2 = scl * blo(u.y); a3 = scl * bhi(u.y);
    }
    int beg = row_ptr[v], end = row_ptr[v + 1];
    int cntE = end - beg;
    int pairs = cntE >> 1;
    int i = 0;
    for (; i + 4 <= pairs; i += 4) {
        int s[4]; float c[4]; uint2 u[4];
#pragma unroll
        for (int t = 0; t < 4; ++t) s[t] = esrc[beg + 2 * (i + t) + half];
#pragma unroll
        for (int t = 0; t < 4; ++t) c[t] = ecw[beg + 2 * (i + t) + half];
#pragma unroll
        for (int t = 0; t < 4; ++t) u[t] = *(const uint2*)(hb + (size_t)s[t] * 128 + 4 * sl);
#pragma unroll
        for (int t = 0; t < 4; ++t) {
            a0 += c[t] * blo(u[t].x); a1 += c[t] * bhi(u[t].x);
            a2 += c[t] * blo(u[t].y); a3 += c[t] * bhi(u[t].y);
        }
    }
    for (; i < pairs; ++i) {
        int s = esrc[beg + 2 * i + half];
        float c = ecw[beg + 2 * i + half];
        uint2 u = *(const uint2*)(hb + (size_t)s * 128 + 4 * sl);
        a0 += c * blo(u.x); a1 += c * bhi(u.x);
        a2 += c * blo(u.y); a3 += c * bhi(u.y);
    }
    if (cntE & 1) {  // tail edge: both halves load it, half 1 weight 0
        int s = esrc[end - 1];
        float c = half ? 0.f : ecw[end - 1];
        uint2 u = *(const uint2*)(hb + (size_t)s * 128 + 4 * sl);
        a0 += c * blo(u.x); a1 += c * bhi(u.x);
        a2 += c * blo(u.y); a3 += c * bhi(u.y);
    }
    // fold halves
    a0 += __shfl_xor(a0, 32); a1 += __shfl_xor(a1, 32);
    a2 += __shfl_xor(a2, 32); a3 += __shfl_xor(a3, 32);

    float4 bv = *(const float4*)(b + 4 * sl);
    float o0 = a0 + bv.x, o1 = a1 + bv.y, o2 = a2 + bv.z, o3 = a3 + bv.w;
    o0 = o0 > 0.f ? o0 : 0.f; o1 = o1 > 0.f ? o1 : 0.f;
    o2 = o2 > 0.f ? o2 : 0.f; o3 = o3 > 0.f ? o3 : 0.f;
    if (lane < 32) {
        uint2 w;
        w.x = (uint)f2b(o0) | ((uint)f2b(o1) << 16);
        w.y = (uint)f2b(o2) | ((uint)f2b(o3) << 16);
        *(uint2*)(out + (size_t)v * 128 + 4 * sl) = w;
    }

    // fused a_s/a_d: dot(g1 row, wa[j]); butterfly within 32 (halves identical)
    float part[16];
#pragma unroll
    for (int j = 0; j < 16; ++j) {
        const float* wj = &swa[j * 128 + 4 * sl];
        part[j] = o0 * wj[0] + o1 * wj[1] + o2 * wj[2] + o3 * wj[3];
    }
#pragma unroll
    for (int m = 1; m < 32; m <<= 1) {
#pragma unroll
        for (int j = 0; j < 16; ++j) part[j] += __shfl_xor(part[j], m);
    }
    if (lane == 0) {
#pragma unroll
        for (int j = 0; j < 8; ++j) {
            a_s[(size_t)v * 8 + j] = part[j];
            a_d[(size_t)v * 8 + j] = part[8 + j];
        }
    }
}

// ------- GAT z aggregation, half-wave edge pairing: lane owns ch 4sl..4sl+3, all 8 heads.
// Lane computes exp for head (lane&7) of its half's edge; broadcast via shfl within half. -------
__global__ __launch_bounds__(256) void gnn_gat_z(const int* __restrict__ row_ptr,
                                                 const int* __restrict__ esrc,
                                                 const float* __restrict__ a_s,
                                                 const float* __restrict__ a_d,
                                                 const ushort* __restrict__ g1b,
                                                 ushort* __restrict__ zb, int n) {
    int v = blockIdx.x * 4 + (threadIdx.x >> 6);
    int lane = threadIdx.x & 63;
    if (v >= n) return;
    const int sl = lane & 31;
    const int half = lane >> 5;
    const int hh = lane & 7;
    const int hbase = lane & 32;  // shfl source base for this half
    const float adh = a_d[(size_t)v * 8 + hh];

    float z0[8] = {}, z1[8] = {}, z2[8] = {}, z3[8] = {};
    float sloc = 0.f;
    {   // self edge (half 0 only)
        float pv = __expf(leaky02(a_s[(size_t)v * 8 + hh] + adh));
        if (half) pv = 0.f;
        sloc += pv;
        uint2 u = *(const uint2*)(g1b + (size_t)v * 128 + 4 * sl);
        float g0 = blo(u.x), g1v = bhi(u.x), g2v = blo(u.y), g3v = bhi(u.y);
        float ph[8];
#pragma unroll
        for (int h = 0; h < 8; ++h) ph[h] = __shfl(pv, hbase | h);
#pragma unroll
        for (int h = 0; h < 8; ++h) {
            z0[h] += ph[h] * g0; z1[h] += ph[h] * g1v;
            z2[h] += ph[h] * g2v; z3[h] += ph[h] * g3v;
        }
    }
    int beg = row_ptr[v], end = row_ptr[v + 1];
    int cntE = end - beg;
    int pairs = cntE >> 1;
    int i = 0;
    for (; i + 2 <= pairs; i += 2) {
        int s[2]; float e[2]; uint2 u[2];
#pragma unroll
        for (int t = 0; t < 2; ++t) s[t] = esrc[beg + 2 * (i + t) + half];
#pragma unroll
        for (int t = 0; t < 2; ++t) e[t] = a_s[(size_t)s[t] * 8 + hh];
#pragma unroll
        for (int t = 0; t < 2; ++t) u[t] = *(const uint2*)(g1b + (size_t)s[t] * 128 + 4 * sl);
#pragma unroll
        for (int t = 0; t < 2; ++t) {
            float pv = __expf(leaky02(e[t] + adh));
            sloc += pv;
            float g0 = blo(u[t].x), g1v = bhi(u[t].x), g2v = blo(u[t].y), g3v = bhi(u[t].y);
            float ph[8];
#pragma unroll
            for (int h = 0; h < 8; ++h) ph[h] = __shfl(pv, hbase | h);
#pragma unroll
            for (int h = 0; h < 8; ++h) {
                z0[h] += ph[h] * g0; z1[h] += ph[h] * g1v;
                z2[h] += ph[h] * g2v; z3[h] += ph[h] * g3v;
            }
        }
    }
    for (; i < pairs; ++i) {
        int s = esrc[beg + 2 * i + half];
        float pv = __expf(leaky02(a_s[(size_t)s * 8 + hh] + adh));
        sloc += pv;
        uint2 u = *(const uint2*)(g1b + (size_t)s * 128 + 4 * sl);
        float g0 = blo(u.x), g1v = bhi(u.x), g2v = blo(u.y), g3v = bhi(u.y);
        float ph[8];
#pragma unroll
        for (int h = 0; h < 8; ++h) ph[h] = __shfl(pv, hbase | h);
#pragma unroll
        for (int h = 0; h < 8; ++h) {
            z0[h] += ph[h] * g0; z1[h] += ph[h] * g1v;
            z2[h] += ph[h] * g2v; z3[h] += ph[h] * g3v;
        }
    }
    if (cntE & 1) {
        int s = esrc[end - 1];
        float pv = __expf(leaky02(a_s[(size_t)s * 8 + hh] + adh));
        if (half) pv = 0.f;
        sloc += pv;
        uint2 u = *(const uint2*)(g1b + (size_t)s * 128 + 4 * sl);
        float g0 = blo(u.x), g1v = bhi(u.x), g2v = blo(u.y), g3v = bhi(u.y);
        float ph[8];
#pragma unroll
        for (int h = 0; h < 8; ++h) ph[h] = __shfl(pv, hbase | h);
#pragma unroll
        for (int h = 0; h < 8; ++h) {
            z0[h] += ph[h] * g0; z1[h] += ph[h] * g1v;
            z2[h] += ph[h] * g2v; z3[h] += ph[h] * g3v;
        }
    }
    // fold halves
    float slx = sloc + __shfl_xor(sloc, 32) + 1e-16f;
#pragma unroll
    for (int h = 0; h < 8; ++h) {
        z0[h] += __shfl_xor(z0[h], 32); z1[h] += __shfl_xor(z1[h], 32);
        z2[h] += __shfl_xor(z2[h], 32); z3[h] += __shfl_xor(z3[h], 32);
    }
    if (lane < 32) {
#pragma unroll
        for (int h = 0; h < 8; ++h) {
            float rs = 1.f / __shfl(slx, h);
            uint2 w;
            w.x = (uint)f2b(z0[h] * rs) | ((uint)f2b(z1[h] * rs) << 16);
            w.y = (uint)f2b(z2[h] * rs) | ((uint)f2b(z3[h] * rs) << 16);
            *(uint2*)(zb + (size_t)v * 1024 + h * 128 + 4 * sl) = w;
        }
    }
}

// ---- GCN2 gather + fused FC -> d_out. Half-wave pairing: lane owns ch 2sl,2sl+1 (uint). ----
__global__ __launch_bounds__(256) void gnn_gcn_node64_fc(const int* __restrict__ row_ptr,
                                                         const int* __restrict__ esrc,
                                                         const float* __restrict__ ecw,
                                                         const float* __restrict__ dinv,
                                                         const ushort* __restrict__ hb,
                                                         const float* __restrict__ b,
                                                         const float* __restrict__ fc_w,
                                                         const float* __restrict__ fc_b,
                                                         float* __restrict__ out, int n) {
    int v = blockIdx.x * 4 + (threadIdx.x >> 6);
    int lane = threadIdx.x & 63;
    if (v >= n) return;
    const int sl = lane & 31;
    const int half = lane >> 5;
    float di = dinv[v];
    float a0, a1;
    {
        float scl = half ? 0.f : di * di;
        uint u = *(const uint*)(hb + (size_t)v * 64 + 2 * sl);
        a0 = scl * blo(u); a1 = scl * bhi(u);
    }
    int beg = row_ptr[v], end = row_ptr[v + 1];
    int cntE = end - beg;
    int pairs = cntE >> 1;
    int i = 0;
    for (; i + 4 <= pairs; i += 4) {
        int s[4]; float c[4]; uint u[4];
#pragma unroll
        for (int t = 0; t < 4; ++t) s[t] = esrc[beg + 2 * (i + t) + half];
#pragma unroll
        for (int t = 0; t < 4; ++t) c[t] = ecw[beg + 2 * (i + t) + half];
#pragma unroll
        for (int t = 0; t < 4; ++t) u[t] = *(const uint*)(hb + (size_t)s[t] * 64 + 2 * sl);
#pragma unroll
        for (int t = 0; t < 4; ++t) { a0 += c[t] * blo(u[t]); a1 += c[t] * bhi(u[t]); }
    }
    for (; i < pairs; ++i) {
        int s = esrc[beg + 2 * i + half];
        float c = ecw[beg + 2 * i + half];
        uint u = *(const uint*)(hb + (size_t)s * 64 + 2 * sl);
        a0 += c * blo(u); a1 += c * bhi(u);
    }
    if (cntE & 1) {
        int s = esrc[end - 1];
        float c = half ? 0.f : ecw[end - 1];
        uint u = *(const uint*)(hb + (size_t)s * 64 + 2 * sl);
        a0 += c * blo(u); a1 += c * bhi(u);
    }
    a0 += __shfl_xor(a0, 32);
    a1 += __shfl_xor(a1, 32);
    float o0 = a0 + b[2 * sl];
    float o1 = a1 + b[2 * sl + 1];
    o0 = o0 > 0.f ? o0 : 0.f;
    o1 = o1 > 0.f ? o1 : 0.f;
    float val = o0 * fc_w[2 * sl] + o1 * fc_w[2 * sl + 1];
#pragma unroll
    for (int m = 1; m < 32; m <<= 1) val += __shfl_xor(val, m);
    if (lane == 0) out[v] = val + fc_b[0];
}

// ---------------- launch ----------------
extern "C" void kernel_launch(void* const* d_in, const int* in_sizes, int n_in,
                              void* d_out, int out_size, void* d_ws, size_t ws_size,
                              hipStream_t stream) {
    const float* x       = (const float*)d_in[0];
    const int*   ei      = (const int*)d_in[1];
    const float* ew      = (const float*)d_in[2];
    const float* gc1_w   = (const float*)d_in[3];
    const float* gc1_b   = (const float*)d_in[4];
    const float* gat_w   = (const float*)d_in[5];
    const float* att_src = (const float*)d_in[6];
    const float* att_dst = (const float*)d_in[7];
    const float* gat_b   = (const float*)d_in[8];
    const float* gc2_w   = (const float*)d_in[9];
    const float* gc2_b   = (const float*)d_in[10];
    const float* fc_w    = (const float*)d_in[11];
    const float* fc_b    = (const float*)d_in[12];
    float* out = (float*)d_out;

    const int N = GNN_N;
    const int E = in_sizes[2];
    const int* src = ei;
    const int* dst = ei + E;

    // ---- workspace layout (~150 MB) ----
    char* p = (char*)d_ws;
    ushort* zb  = (ushort*)p; p += (size_t)N * 1024 * 2;  // 102.4 MB [N][8*128] bf16
    ushort* h1b = (ushort*)p; p += (size_t)N * 128 * 2;   // 12.8 MB
    ushort* g1b = (ushort*)p; p += (size_t)N * 128 * 2;   // 12.8 MB
    ushort* g2b = (ushort*)p; p += (size_t)N * 64 * 2;    // 6.4 MB
    ushort* h3b = (ushort*)p; p += (size_t)N * 64 * 2;    // 6.4 MB
    ushort* w1t = (ushort*)p; p += (size_t)128 * 256 * 2; // 64 KB
    ushort* w2s_t = (ushort*)p; p += (size_t)64 * 1024 * 2; // 128 KB
    ushort* w3t = (ushort*)p; p += (size_t)64 * 64 * 2;   // 8 KB
    float*  wa_t = (float*)p; p += 16 * 128 * 4;          // 8 KB
    float*  a_s = (float*)p;  p += (size_t)N * 8 * 4;
    float*  a_d = (float*)p;  p += (size_t)N * 8 * 4;
    int* row_ptr = (int*)p;   p += (size_t)(N + 64) * 4;
    int* esrc = (int*)p;      p += (size_t)E * 4;
    float* ecw = (float*)p;   p += (size_t)E * 4;
    int* cnt = (int*)p;       p += (size_t)N * 4;
    int* fill = (int*)p;      p += (size_t)N * 4;
    float* dinv = (float*)p;  p += (size_t)N * 4;
    int* blksum = (int*)p;    p += 4096;

    auto cdiv = [](long a, long b) { return (int)((a + b - 1) / b); };

    // ---- CSR build + symmetric norm ----
    hipMemsetAsync(cnt, 0, (size_t)N * 12, stream);  // cnt + fill + dinv(acc)
    gnn_hist<<<cdiv(E, 256), 256, 0, stream>>>(dst, ew, cnt, dinv, E);
    gnn_deg_fin<<<cdiv(N, 256), 256, 0, stream>>>(dinv, N);
    const int nblk = cdiv(N, 1024);
    gnn_scan1<<<nblk, 256, 0, stream>>>(cnt, row_ptr, blksum, N);
    gnn_scan2<<<1, 64, 0, stream>>>(blksum, nblk, row_ptr + N, E);
    gnn_scan3<<<cdiv(N, 256), 256, 0, stream>>>(row_ptr, blksum, N);
    gnn_scatter<<<cdiv(E, 256), 256, 0, stream>>>(src, dst, ew, dinv, row_ptr, fill, esrc, ecw, E);

    // ---- fused prep ----
    gnn_prep<<<408, 256, 0, stream>>>(gc1_w, gat_w, gc2_w, att_src, att_dst, w1t, w2s_t, w3t, wa_t);

    // ---- GCN1: h1b = bf16(x @ gc1_w); gather + fused asd ----
    {
        dim3 grid(128 / 64, cdiv(N, 64));
        gnn_mfma_gemm<true, false><<<grid, 256, 0, stream>>>(x, w1t, h1b, nullptr, N, 128, 256);
    }
    gnn_gcn_node128_asd<<<cdiv(N, 4), 256, 0, stream>>>(row_ptr, esrc, ecw, dinv, h1b, gc1_b,
                                                        wa_t, g1b, a_s, a_d, N);

    // ---- GAT: z-space aggregation then stacked GEMM (bias+relu fused) ----
    gnn_gat_z<<<cdiv(N, 4), 256, 0, stream>>>(row_ptr, esrc, a_s, a_d, g1b, zb, N);
    {
        dim3 grid(1, cdiv(N, 64));
        gnn_mfma_gemm<false, true><<<grid, 256, 0, stream>>>(zb, w2s_t, g2b, gat_b, N, 64, 1024);
    }

    // ---- GCN2 + FC ----
    {
        dim3 grid(1, cdiv(N, 64));
        gnn_mfma_gemm<false, false><<<grid, 256, 0, stream>>>(g2b, w3t, h3b, nullptr, N, 64, 64);
    }
    gnn_gcn_node64_fc<<<cdiv(N, 4), 256, 0, stream>>>(row_ptr, esrc, ecw, dinv, h3b, gc2_b,
                                                      fc_w, fc_b, out, N);
}